// Round 2
// baseline (649.229 us; speedup 1.0000x reference)
//
#include <hip/hip_runtime.h>
#include <hip/hip_fp16.h>
#include <math.h>

#define NEG_SLOPE 0.2f
#define BN_EPS_F 1e-5f
#define NUM_G 500

__device__ __forceinline__ float leaky(float x){ return x > 0.f ? x : NEG_SLOPE*x; }
__device__ __forceinline__ float sel4(int h, float a, float b, float c, float d){
  float r = a; r = (h==1)? b : r; r = (h==2)? c : r; r = (h==3)? d : r; return r;
}
__device__ __forceinline__ float bcast(float v, int k){
  return __int_as_float(__builtin_amdgcn_readlane(__float_as_int(v), k));
}

// ---------------- linear 1: xh1 = x @ W1 (fp16 out), plus per-head att dots ----------------
// W1 columns in registers (32 VGPRs/lane), x row broadcast via readlane.
__global__ __launch_bounds__(256) void lin1_kernel(
    const float* __restrict__ x, const float* __restrict__ W,
    const float* __restrict__ att_s, const float* __restrict__ att_d,
    __half* __restrict__ xh, float* __restrict__ a_src, float* __restrict__ a_dst, int N)
{
  int lane = threadIdx.x & 63;
  int wid  = (blockIdx.x * blockDim.x + threadIdx.x) >> 6;
  int nw   = (gridDim.x * blockDim.x) >> 6;
  float w[32];
  #pragma unroll
  for (int k = 0; k < 32; ++k) w[k] = W[k*64 + lane];
  float asv = att_s[lane], adv = att_d[lane];
  for (int n = wid; n < N; n += nw) {
    float xv = (lane < 32) ? x[(size_t)n*32 + lane] : 0.f;
    float acc = 0.f;
    #pragma unroll
    for (int k = 0; k < 32; ++k) acc = fmaf(bcast(xv, k), w[k], acc);
    float sv = acc*asv, dv = acc*adv;
    #pragma unroll
    for (int m = 1; m < 16; m <<= 1) { sv += __shfl_xor(sv, m); dv += __shfl_xor(dv, m); }
    xh[(size_t)n*64 + lane] = __float2half(acc);
    if ((lane & 15) == 0) { a_src[n*4 + (lane>>4)] = sv; a_dst[n*4 + (lane>>4)] = dv; }
  }
}

// ---------------- linear 2: xh2 = h1 @ W2 (fp16 out), plus att dots ----------------
// Lane owns channels (lane) and (lane+64): 128 W VGPRs; h row broadcast via readlane.
__global__ __launch_bounds__(256) void lin2_kernel(
    const float* __restrict__ hin, const float* __restrict__ W,
    const float* __restrict__ att_s, const float* __restrict__ att_d,
    __half* __restrict__ xh, float* __restrict__ a_src, float* __restrict__ a_dst, int N)
{
  int lane = threadIdx.x & 63;
  int wid  = (blockIdx.x * blockDim.x + threadIdx.x) >> 6;
  int nw   = (gridDim.x * blockDim.x) >> 6;
  float wa[64], wb[64];
  #pragma unroll
  for (int k = 0; k < 64; ++k) { wa[k] = W[k*128 + lane]; wb[k] = W[k*128 + 64 + lane]; }
  float asa = att_s[lane], ada = att_d[lane];
  float asb = att_s[64+lane], adb = att_d[64+lane];
  for (int n = wid; n < N; n += nw) {
    float hv = hin[(size_t)n*64 + lane];
    float a0 = 0.f, a1 = 0.f;
    #pragma unroll
    for (int k = 0; k < 64; ++k) {
      float h = bcast(hv, k);
      a0 = fmaf(h, wa[k], a0); a1 = fmaf(h, wb[k], a1);
    }
    float sva = a0*asa, dva = a0*ada, svb = a1*asb, dvb = a1*adb;
    #pragma unroll
    for (int m = 1; m < 32; m <<= 1) {
      sva += __shfl_xor(sva, m); dva += __shfl_xor(dva, m);
      svb += __shfl_xor(svb, m); dvb += __shfl_xor(dvb, m);
    }
    xh[(size_t)n*128 + lane] = __float2half(a0);
    xh[(size_t)n*128 + 64 + lane] = __float2half(a1);
    if ((lane & 31) == 0) {
      int hh = lane >> 5;
      a_src[n*4 + hh] = sva;     a_dst[n*4 + hh] = dva;
      a_src[n*4 + 2 + hh] = svb; a_dst[n*4 + 2 + hh] = dvb;
    }
  }
}

// ---------------- histogram (deg-by-dst and batch counts) ----------------
__global__ void hist_kernel(const int* __restrict__ idx, int* __restrict__ cnt, int n)
{
  int i = blockIdx.x*blockDim.x + threadIdx.x;
  int stride = gridDim.x*blockDim.x;
  for (; i < n; i += stride) atomicAdd(&cnt[idx[i]], 1);
}

// ---------------- two exclusive scans in one launch (block 0: deg, block 1: gcnt) ----------------
__global__ __launch_bounds__(1024) void exscan2_kernel(
    const int* __restrict__ in0, int* __restrict__ out0, int n0,
    const int* __restrict__ in1, int* __restrict__ out1, int n1)
{
  const int* in  = blockIdx.x ? in1  : in0;
  int*       out = blockIdx.x ? out1 : out0;
  int        n   = blockIdx.x ? n1   : n0;
  __shared__ int part[1024];
  int t = threadIdx.x;
  int per = (n + 1023) >> 10;
  int lo = t*per, hi = lo + per; if (hi > n) hi = n; if (lo > n) lo = n;
  int s = 0;
  for (int i = lo; i < hi; ++i) s += in[i];
  part[t] = s;
  __syncthreads();
  for (int ofs = 1; ofs < 1024; ofs <<= 1) {
    int v = (t >= ofs) ? part[t-ofs] : 0;
    __syncthreads();
    part[t] += v;
    __syncthreads();
  }
  int base = part[t] - s;
  for (int i = lo; i < hi; ++i) { out[i] = base; base += in[i]; }
  if (t == 1023) out[n] = part[1023];
}

// ---------------- CSR scatter ----------------
__global__ void scatter_kernel(const int* __restrict__ src, const int* __restrict__ dst,
    const int* __restrict__ off, int* __restrict__ cursor, int* __restrict__ csr, int E)
{
  int i = blockIdx.x*blockDim.x + threadIdx.x;
  int stride = gridDim.x*blockDim.x;
  for (; i < E; i += stride) {
    int d = dst[i];
    int pos = off[d] + atomicAdd(&cursor[d], 1);
    csr[pos] = src[i];
  }
}

// ---------------- GAT aggregation per node (single fused pass) ----------------
// No max-subtraction (scores bounded, softmax shift-invariant). Per 64-edge chunk:
// lanes stage exp(score) + src into LDS (4 exps/edge total), then all lanes gather
// fp16 xh rows weighted by LDS-broadcast w. Normalize once at the end; fused
// bias+BN+ReLU (+pool gate for layer 2).
template<int CP, bool GATE>   // F = 64*CP channels
__global__ __launch_bounds__(64) void gat_agg_kernel(
    const __half* __restrict__ xh, const float* __restrict__ a_src, const float* __restrict__ a_dst,
    const int* __restrict__ off, const int* __restrict__ csr,
    const float* __restrict__ bias, const float* __restrict__ bng, const float* __restrict__ bnb,
    const float* __restrict__ bnrm, const float* __restrict__ bnrv,
    const float* __restrict__ gateW, const float* __restrict__ gateB,
    float* __restrict__ hout, float* __restrict__ gate, int N)
{
  constexpr int F = 64*CP;
  __shared__ float p_lds[64][4];
  __shared__ int   s_lds[64];
  int lane = threadIdx.x;
  const float4* as4 = (const float4*)a_src;
  const float4* ad4 = (const float4*)a_dst;
  for (int n = blockIdx.x; n < N; n += gridDim.x) {
    int lo = off[n], cnt = off[n+1] - lo;
    float4 asn = as4[n], adn = ad4[n];
    float es0 = __expf(leaky(asn.x+adn.x)), es1 = __expf(leaky(asn.y+adn.y));
    float es2 = __expf(leaky(asn.z+adn.z)), es3 = __expf(leaky(asn.w+adn.w));
    float s0=0.f, s1=0.f, s2=0.f, s3=0.f;
    float accx=0.f, accy=0.f;
    for (int base = 0; base < cnt; base += 64) {
      int rem = cnt - base; if (rem > 64) rem = 64;
      if (lane < rem) {
        int s = csr[lo + base + lane];
        float4 a = as4[s];
        float w0=__expf(leaky(a.x+adn.x)), w1=__expf(leaky(a.y+adn.y));
        float w2=__expf(leaky(a.z+adn.z)), w3=__expf(leaky(a.w+adn.w));
        s0+=w0; s1+=w1; s2+=w2; s3+=w3;
        s_lds[lane]=s;
        p_lds[lane][0]=w0; p_lds[lane][1]=w1; p_lds[lane][2]=w2; p_lds[lane][3]=w3;
      }
      __syncthreads();
      if (CP == 2) {
        int c2 = 2*lane, h = lane>>4;
        for (int e = 0; e < rem; ++e) {
          int s = s_lds[e];
          float wv = p_lds[e][h];
          float2 v = __half22float2(*(const __half2*)(xh + (size_t)s*F + c2));
          accx = fmaf(wv, v.x, accx); accy = fmaf(wv, v.y, accy);
        }
      } else {
        int sub = lane>>5, c2 = 2*(lane&31), h = c2>>4;
        for (int e = sub; e < rem; e += 2) {
          int s = s_lds[e];
          float wv = p_lds[e][h];
          float2 v = __half22float2(*(const __half2*)(xh + (size_t)s*F + c2));
          accx = fmaf(wv, v.x, accx); accy = fmaf(wv, v.y, accy);
        }
      }
      __syncthreads();
    }
    #pragma unroll
    for (int m = 1; m < 64; m <<= 1) {
      s0 += __shfl_xor(s0,m); s1 += __shfl_xor(s1,m);
      s2 += __shfl_xor(s2,m); s3 += __shfl_xor(s3,m);
    }
    s0+=es0; s1+=es1; s2+=es2; s3+=es3;
    float i0=1.f/(s0+1e-16f), i1=1.f/(s1+1e-16f), i2=1.f/(s2+1e-16f), i3=1.f/(s3+1e-16f);
    if (CP == 2) {
      int c2 = 2*lane, h = lane>>4;
      float esh = sel4(h, es0,es1,es2,es3);
      float inv = sel4(h, i0,i1,i2,i3);
      float2 v = __half22float2(*(const __half2*)(xh + (size_t)n*F + c2));
      float r0 = (accx + esh*v.x)*inv + bias[c2];
      float r1 = (accy + esh*v.y)*inv + bias[c2+1];
      r0 = fmaxf((r0 - bnrm[c2  ]) * rsqrtf(bnrv[c2  ]+BN_EPS_F) * bng[c2  ] + bnb[c2  ], 0.f);
      r1 = fmaxf((r1 - bnrm[c2+1]) * rsqrtf(bnrv[c2+1]+BN_EPS_F) * bng[c2+1] + bnb[c2+1], 0.f);
      *(float2*)(hout + (size_t)n*F + c2) = make_float2(r0, r1);
      if (GATE) {
        float gl = r0*gateW[c2] + r1*gateW[c2+1];
        #pragma unroll
        for (int m = 1; m < 64; m <<= 1) gl += __shfl_xor(gl, m);
        if (lane == 0) gate[n] = gl + gateB[0];
      }
    } else {
      accx += __shfl_xor(accx, 32); accy += __shfl_xor(accy, 32);
      if (lane < 32) {
        int c2 = 2*lane, h = c2>>4;
        float esh = sel4(h, es0,es1,es2,es3);
        float inv = sel4(h, i0,i1,i2,i3);
        float2 v = __half22float2(*(const __half2*)(xh + (size_t)n*F + c2));
        float r0 = (accx + esh*v.x)*inv + bias[c2];
        float r1 = (accy + esh*v.y)*inv + bias[c2+1];
        r0 = fmaxf((r0 - bnrm[c2  ]) * rsqrtf(bnrv[c2  ]+BN_EPS_F) * bng[c2  ] + bnb[c2  ], 0.f);
        r1 = fmaxf((r1 - bnrm[c2+1]) * rsqrtf(bnrv[c2+1]+BN_EPS_F) * bng[c2+1] + bnb[c2+1], 0.f);
        *(float2*)(hout + (size_t)n*F + c2) = make_float2(r0, r1);
      }
    }
  }
}

// ---------------- per-graph attention pooling + MLP heads ----------------
__global__ __launch_bounds__(128) void pool_kernel(
    const float* __restrict__ h2, const float* __restrict__ gate, const int* __restrict__ goff,
    const float* __restrict__ fc1W, const float* __restrict__ fc1b,
    const float* __restrict__ valW, const float* __restrict__ valb,
    const float* __restrict__ advW, const float* __restrict__ advb,
    float* __restrict__ out)
{
  int g = blockIdx.x, t = threadIdx.x;
  int lo = goff[g], hi = goff[g+1];
  __shared__ float red[2];
  __shared__ float pld[128];
  __shared__ float zs[32];
  __shared__ float sval;
  __shared__ float adv_s[16];

  float m = -3.4e38f;
  for (int n = lo+t; n < hi; n += 128) m = fmaxf(m, gate[n]);
  #pragma unroll
  for (int msk = 1; msk < 64; msk <<= 1) m = fmaxf(m, __shfl_xor(m, msk));
  if ((t & 63) == 0) red[t >> 6] = m;
  __syncthreads();
  m = fmaxf(red[0], red[1]);
  __syncthreads();
  float sl = 0.f;
  for (int n = lo+t; n < hi; n += 128) sl += __expf(gate[n]-m);
  #pragma unroll
  for (int msk = 1; msk < 64; msk <<= 1) sl += __shfl_xor(sl, msk);
  if ((t & 63) == 0) red[t >> 6] = sl;
  __syncthreads();
  float s = red[0] + red[1];
  float acc = 0.f;
  for (int n = lo; n < hi; ++n) {
    float w = __expf(gate[n]-m);
    acc += w * h2[(size_t)n*128 + t];
  }
  pld[t] = acc / (s + 1e-16f);
  __syncthreads();
  if (t < 32) {
    float z = fc1b[t];
    #pragma unroll 4
    for (int k = 0; k < 128; ++k) z += pld[k]*fc1W[k*32 + t];
    zs[t] = fmaxf(z, 0.f);
  }
  __syncthreads();
  if (t < 32) {
    float pv = zs[t]*valW[t];
    #pragma unroll
    for (int msk = 1; msk < 32; msk <<= 1) pv += __shfl_xor(pv, msk);
    if (t == 0) sval = pv + valb[0];
  }
  if (t < 16) {
    float a = advb[t];
    #pragma unroll
    for (int k = 0; k < 32; ++k) a += zs[k]*advW[k*16 + t];
    adv_s[t] = a;
  }
  __syncthreads();
  if (t < 16) {
    float amean = adv_s[t];
    #pragma unroll
    for (int msk = 1; msk < 16; msk <<= 1) amean += __shfl_xor(amean, msk);
    amean *= (1.f/16.f);
    out[g*16 + t] = sval + adv_s[t] - amean;
  }
}

extern "C" void kernel_launch(void* const* d_in, const int* in_sizes, int n_in,
                              void* d_out, int out_size, void* d_ws, size_t ws_size,
                              hipStream_t stream)
{
  const float* x     = (const float*)d_in[0];
  const int*   eidx  = (const int*)  d_in[1];
  const int*   batch = (const int*)  d_in[2];
  const float* W1    = (const float*)d_in[3];
  const float* as1w  = (const float*)d_in[4];
  const float* ad1w  = (const float*)d_in[5];
  const float* b1    = (const float*)d_in[6];
  const float* bn1g  = (const float*)d_in[7];
  const float* bn1b  = (const float*)d_in[8];
  const float* bn1rm = (const float*)d_in[9];
  const float* bn1rv = (const float*)d_in[10];
  const float* W2    = (const float*)d_in[11];
  const float* as2w  = (const float*)d_in[12];
  const float* ad2w  = (const float*)d_in[13];
  const float* b2    = (const float*)d_in[14];
  const float* bn2g  = (const float*)d_in[15];
  const float* bn2b  = (const float*)d_in[16];
  const float* bn2rm = (const float*)d_in[17];
  const float* bn2rv = (const float*)d_in[18];
  const float* gateW = (const float*)d_in[19];
  const float* gateB = (const float*)d_in[20];
  const float* fc1W  = (const float*)d_in[21];
  const float* fc1b  = (const float*)d_in[22];
  const float* valW  = (const float*)d_in[23];
  const float* valb  = (const float*)d_in[24];
  const float* advW  = (const float*)d_in[25];
  const float* advb  = (const float*)d_in[26];

  int N = in_sizes[0] / 32;
  int E = in_sizes[1] / 2;
  const int* esrc = eidx;
  const int* edst = eidx + E;

  float* ws = (float*)d_ws;
  size_t o = 0;
  __half* xh1h = (__half*)(ws + o); o += (size_t)N*32;   // N*64 halves
  __half* xh2h = (__half*)(ws + o); o += (size_t)N*64;   // N*128 halves
  float* as1 = ws + o; o += (size_t)N*4;
  float* ad1 = ws + o; o += (size_t)N*4;
  float* as2 = ws + o; o += (size_t)N*4;
  float* ad2 = ws + o; o += (size_t)N*4;
  float* h1  = ws + o; o += (size_t)N*64;
  float* h2  = ws + o; o += (size_t)N*128;
  float* gate = ws + o; o += (size_t)N;
  int* ib     = (int*)(ws + o);
  int* deg    = ib;                        // N
  int* cursor = ib + N;                    // N
  int* gcnt   = ib + 2*(size_t)N;          // NUM_G (deg..gcnt zeroed together)
  int* off    = ib + 2*(size_t)N + NUM_G;  // N+1
  int* goff   = off + (N+1);               // NUM_G+1
  int* csr    = goff + (NUM_G+1);          // E

  hipMemsetAsync(deg, 0, (size_t)(2*(size_t)N + NUM_G)*sizeof(int), stream);

  lin1_kernel<<<256, 256, 0, stream>>>(x, W1, as1w, ad1w, xh1h, as1, ad1, N);
  hist_kernel<<<1024, 256, 0, stream>>>(edst, deg, E);
  hist_kernel<<<256, 256, 0, stream>>>(batch, gcnt, N);
  exscan2_kernel<<<2, 1024, 0, stream>>>(deg, off, N, gcnt, goff, NUM_G);
  scatter_kernel<<<1024, 256, 0, stream>>>(esrc, edst, off, cursor, csr, E);
  gat_agg_kernel<1,false><<<4096, 64, 0, stream>>>(xh1h, as1, ad1, off, csr,
      b1, bn1g, bn1b, bn1rm, bn1rv, nullptr, nullptr, h1, nullptr, N);
  lin2_kernel<<<256, 256, 0, stream>>>(h1, W2, as2w, ad2w, xh2h, as2, ad2, N);
  gat_agg_kernel<2,true><<<4096, 64, 0, stream>>>(xh2h, as2, ad2, off, csr,
      b2, bn2g, bn2b, bn2rm, bn2rv, gateW, gateB, h2, gate, N);
  pool_kernel<<<NUM_G, 128, 0, stream>>>(h2, gate, goff, fc1W, fc1b, valW, valb, advW, advb,
      (float*)d_out);
}

// Round 3
// 488.472 us; speedup vs baseline: 1.3291x; 1.3291x over previous
//
#include <hip/hip_runtime.h>
#include <hip/hip_fp16.h>
#include <math.h>

#define NEG_SLOPE 0.2f
#define BN_EPS_F 1e-5f
#define NUM_G 500

__device__ __forceinline__ float leaky(float x){ return x > 0.f ? x : NEG_SLOPE*x; }
__device__ __forceinline__ float bcast(float v, int k){
  return __int_as_float(__builtin_amdgcn_readlane(__float_as_int(v), k));
}

// ---------------- linear 1: xh1 = x @ W1 (fp16 out), plus per-head att dots ----------------
__global__ __launch_bounds__(256) void lin1_kernel(
    const float* __restrict__ x, const float* __restrict__ W,
    const float* __restrict__ att_s, const float* __restrict__ att_d,
    __half* __restrict__ xh, float* __restrict__ a_src, float* __restrict__ a_dst, int N)
{
  int lane = threadIdx.x & 63;
  int wid  = (blockIdx.x * blockDim.x + threadIdx.x) >> 6;
  int nw   = (gridDim.x * blockDim.x) >> 6;
  float w[32];
  #pragma unroll
  for (int k = 0; k < 32; ++k) w[k] = W[k*64 + lane];
  float asv = att_s[lane], adv = att_d[lane];
  for (int n = wid; n < N; n += nw) {
    float xv = (lane < 32) ? x[(size_t)n*32 + lane] : 0.f;
    float acc = 0.f;
    #pragma unroll
    for (int k = 0; k < 32; ++k) acc = fmaf(bcast(xv, k), w[k], acc);
    float sv = acc*asv, dv = acc*adv;
    #pragma unroll
    for (int m = 1; m < 16; m <<= 1) { sv += __shfl_xor(sv, m); dv += __shfl_xor(dv, m); }
    xh[(size_t)n*64 + lane] = __float2half(acc);
    if ((lane & 15) == 0) { a_src[n*4 + (lane>>4)] = sv; a_dst[n*4 + (lane>>4)] = dv; }
  }
}

// ---------------- linear 2: xh2 = h1 @ W2 (fp16 out), plus att dots ----------------
__global__ __launch_bounds__(256) void lin2_kernel(
    const float* __restrict__ hin, const float* __restrict__ W,
    const float* __restrict__ att_s, const float* __restrict__ att_d,
    __half* __restrict__ xh, float* __restrict__ a_src, float* __restrict__ a_dst, int N)
{
  int lane = threadIdx.x & 63;
  int wid  = (blockIdx.x * blockDim.x + threadIdx.x) >> 6;
  int nw   = (gridDim.x * blockDim.x) >> 6;
  float wa[64], wb[64];
  #pragma unroll
  for (int k = 0; k < 64; ++k) { wa[k] = W[k*128 + lane]; wb[k] = W[k*128 + 64 + lane]; }
  float asa = att_s[lane], ada = att_d[lane];
  float asb = att_s[64+lane], adb = att_d[64+lane];
  for (int n = wid; n < N; n += nw) {
    float hv = hin[(size_t)n*64 + lane];
    float a0 = 0.f, a1 = 0.f;
    #pragma unroll
    for (int k = 0; k < 64; ++k) {
      float h = bcast(hv, k);
      a0 = fmaf(h, wa[k], a0); a1 = fmaf(h, wb[k], a1);
    }
    float sva = a0*asa, dva = a0*ada, svb = a1*asb, dvb = a1*adb;
    #pragma unroll
    for (int m = 1; m < 32; m <<= 1) {
      sva += __shfl_xor(sva, m); dva += __shfl_xor(dva, m);
      svb += __shfl_xor(svb, m); dvb += __shfl_xor(dvb, m);
    }
    xh[(size_t)n*128 + lane] = __float2half(a0);
    xh[(size_t)n*128 + 64 + lane] = __float2half(a1);
    if ((lane & 31) == 0) {
      int hh = lane >> 5;
      a_src[n*4 + hh] = sva;     a_dst[n*4 + hh] = dva;
      a_src[n*4 + 2 + hh] = svb; a_dst[n*4 + 2 + hh] = dvb;
    }
  }
}

// ---------------- histogram ----------------
__global__ void hist_kernel(const int* __restrict__ idx, int* __restrict__ cnt, int n)
{
  int i = blockIdx.x*blockDim.x + threadIdx.x;
  int stride = gridDim.x*blockDim.x;
  for (; i < n; i += stride) atomicAdd(&cnt[idx[i]], 1);
}

// ---------------- two exclusive scans in one launch ----------------
__global__ __launch_bounds__(1024) void exscan2_kernel(
    const int* __restrict__ in0, int* __restrict__ out0, int n0,
    const int* __restrict__ in1, int* __restrict__ out1, int n1)
{
  const int* in  = blockIdx.x ? in1  : in0;
  int*       out = blockIdx.x ? out1 : out0;
  int        n   = blockIdx.x ? n1   : n0;
  __shared__ int part[1024];
  int t = threadIdx.x;
  int per = (n + 1023) >> 10;
  int lo = t*per, hi = lo + per; if (hi > n) hi = n; if (lo > n) lo = n;
  int s = 0;
  for (int i = lo; i < hi; ++i) s += in[i];
  part[t] = s;
  __syncthreads();
  for (int ofs = 1; ofs < 1024; ofs <<= 1) {
    int v = (t >= ofs) ? part[t-ofs] : 0;
    __syncthreads();
    part[t] += v;
    __syncthreads();
  }
  int base = part[t] - s;
  for (int i = lo; i < hi; ++i) { out[i] = base; base += in[i]; }
  if (t == 1023) out[n] = part[1023];
}

// ---------------- CSR scatter ----------------
__global__ void scatter_kernel(const int* __restrict__ src, const int* __restrict__ dst,
    const int* __restrict__ off, int* __restrict__ cursor, int* __restrict__ csr, int E)
{
  int i = blockIdx.x*blockDim.x + threadIdx.x;
  int stride = gridDim.x*blockDim.x;
  for (; i < E; i += stride) {
    int d = dst[i];
    int pos = off[d] + atomicAdd(&cursor[d], 1);
    csr[pos] = src[i];
  }
}

// ---------------- GAT agg layer 1: F=64, one wave per node, single fused pass ----------------
// Lane owns channel `lane`, head lane>>4. Every lane walks ALL edges -> per-head sums are
// computed redundantly within head groups => no shuffles/LDS/barriers needed.
__global__ __launch_bounds__(256) void gat_agg1_kernel(
    const __half* __restrict__ xh, const float* __restrict__ a_src, const float* __restrict__ a_dst,
    const int* __restrict__ off, const int* __restrict__ csr,
    const float* __restrict__ bias, const float* __restrict__ bng, const float* __restrict__ bnb,
    const float* __restrict__ bnrm, const float* __restrict__ bnrv,
    float* __restrict__ hout, int N)
{
  int lane = threadIdx.x & 63;
  int wid  = (blockIdx.x * blockDim.x + threadIdx.x) >> 6;
  int nw   = (gridDim.x * blockDim.x) >> 6;
  int h = lane >> 4;
  float sc  = rsqrtf(bnrv[lane]+BN_EPS_F) * bng[lane];
  float ofc = bias[lane]*sc + bnb[lane] - bnrm[lane]*sc;
  for (int n = wid; n < N; n += nw) {
    int e = off[n], hi = off[n+1];
    float adh = a_dst[n*4+h];
    float es  = __expf(leaky(a_src[n*4+h] + adh));
    float acc = 0.f, ssum = 0.f;
    for (; e+3 < hi; e += 4) {
      int s0=csr[e], s1=csr[e+1], s2=csr[e+2], s3=csr[e+3];
      float a0=a_src[s0*4+h], a1=a_src[s1*4+h], a2=a_src[s2*4+h], a3=a_src[s3*4+h];
      float v0=__half2float(xh[(size_t)s0*64+lane]);
      float v1=__half2float(xh[(size_t)s1*64+lane]);
      float v2=__half2float(xh[(size_t)s2*64+lane]);
      float v3=__half2float(xh[(size_t)s3*64+lane]);
      float w0=__expf(leaky(a0+adh)), w1=__expf(leaky(a1+adh));
      float w2=__expf(leaky(a2+adh)), w3=__expf(leaky(a3+adh));
      ssum += (w0+w1)+(w2+w3);
      acc = fmaf(w0,v0,acc); acc = fmaf(w1,v1,acc);
      acc = fmaf(w2,v2,acc); acc = fmaf(w3,v3,acc);
    }
    for (; e < hi; ++e) {
      int s = csr[e];
      float a = a_src[s*4+h];
      float v = __half2float(xh[(size_t)s*64+lane]);
      float w = __expf(leaky(a+adh));
      ssum += w; acc = fmaf(w,v,acc);
    }
    float vs = __half2float(xh[(size_t)n*64+lane]);
    acc  = fmaf(es, vs, acc);
    ssum += es;
    float val = acc / (ssum + 1e-16f);
    hout[(size_t)n*64+lane] = fmaxf(fmaf(val, sc, ofc), 0.f);
  }
}

// ---------------- GAT agg layer 2: F=128 via half2 (lane owns 2 ch), + pool gate ----------------
__global__ __launch_bounds__(256) void gat_agg2_kernel(
    const __half* __restrict__ xh, const float* __restrict__ a_src, const float* __restrict__ a_dst,
    const int* __restrict__ off, const int* __restrict__ csr,
    const float* __restrict__ bias, const float* __restrict__ bng, const float* __restrict__ bnb,
    const float* __restrict__ bnrm, const float* __restrict__ bnrv,
    const float* __restrict__ gateW, const float* __restrict__ gateB,
    float* __restrict__ hout, float* __restrict__ gate, int N)
{
  int lane = threadIdx.x & 63;
  int wid  = (blockIdx.x * blockDim.x + threadIdx.x) >> 6;
  int nw   = (gridDim.x * blockDim.x) >> 6;
  int c2 = 2*lane, h = lane >> 4;
  float sc0  = rsqrtf(bnrv[c2  ]+BN_EPS_F) * bng[c2  ];
  float of0  = bias[c2  ]*sc0 + bnb[c2  ] - bnrm[c2  ]*sc0;
  float sc1  = rsqrtf(bnrv[c2+1]+BN_EPS_F) * bng[c2+1];
  float of1  = bias[c2+1]*sc1 + bnb[c2+1] - bnrm[c2+1]*sc1;
  float gw0 = gateW[c2], gw1 = gateW[c2+1], gb = gateB[0];
  const __half2* xhv = (const __half2*)xh;   // row stride 64 half2
  for (int n = wid; n < N; n += nw) {
    int e = off[n], hi = off[n+1];
    float adh = a_dst[n*4+h];
    float es  = __expf(leaky(a_src[n*4+h] + adh));
    float accx = 0.f, accy = 0.f, ssum = 0.f;
    for (; e+3 < hi; e += 4) {
      int s0=csr[e], s1=csr[e+1], s2=csr[e+2], s3=csr[e+3];
      float a0=a_src[s0*4+h], a1=a_src[s1*4+h], a2=a_src[s2*4+h], a3=a_src[s3*4+h];
      __half2 v0 = xhv[(size_t)s0*64 + lane];
      __half2 v1 = xhv[(size_t)s1*64 + lane];
      __half2 v2 = xhv[(size_t)s2*64 + lane];
      __half2 v3 = xhv[(size_t)s3*64 + lane];
      float w0=__expf(leaky(a0+adh)), w1=__expf(leaky(a1+adh));
      float w2=__expf(leaky(a2+adh)), w3=__expf(leaky(a3+adh));
      ssum += (w0+w1)+(w2+w3);
      float2 f0=__half22float2(v0), f1=__half22float2(v1);
      float2 f2=__half22float2(v2), f3=__half22float2(v3);
      accx = fmaf(w0,f0.x,accx); accy = fmaf(w0,f0.y,accy);
      accx = fmaf(w1,f1.x,accx); accy = fmaf(w1,f1.y,accy);
      accx = fmaf(w2,f2.x,accx); accy = fmaf(w2,f2.y,accy);
      accx = fmaf(w3,f3.x,accx); accy = fmaf(w3,f3.y,accy);
    }
    for (; e < hi; ++e) {
      int s = csr[e];
      float a = a_src[s*4+h];
      __half2 v = xhv[(size_t)s*64 + lane];
      float w = __expf(leaky(a+adh));
      float2 f = __half22float2(v);
      ssum += w; accx = fmaf(w,f.x,accx); accy = fmaf(w,f.y,accy);
    }
    float2 fs = __half22float2(xhv[(size_t)n*64 + lane]);
    accx = fmaf(es, fs.x, accx); accy = fmaf(es, fs.y, accy);
    ssum += es;
    float inv = 1.f / (ssum + 1e-16f);
    float r0 = fmaxf(fmaf(accx*inv, sc0, of0), 0.f);
    float r1 = fmaxf(fmaf(accy*inv, sc1, of1), 0.f);
    *(float2*)(hout + (size_t)n*128 + c2) = make_float2(r0, r1);
    float gl = r0*gw0 + r1*gw1;
    #pragma unroll
    for (int m = 1; m < 64; m <<= 1) gl += __shfl_xor(gl, m);
    if (lane == 0) gate[n] = gl + gb;
  }
}

// ---------------- per-graph attention pooling + MLP heads ----------------
__global__ __launch_bounds__(128) void pool_kernel(
    const float* __restrict__ h2, const float* __restrict__ gate, const int* __restrict__ goff,
    const float* __restrict__ fc1W, const float* __restrict__ fc1b,
    const float* __restrict__ valW, const float* __restrict__ valb,
    const float* __restrict__ advW, const float* __restrict__ advb,
    float* __restrict__ out)
{
  int g = blockIdx.x, t = threadIdx.x;
  int lo = goff[g], hi = goff[g+1];
  __shared__ float red[2];
  __shared__ float pld[128];
  __shared__ float zs[32];
  __shared__ float sval;
  __shared__ float adv_s[16];

  float m = -3.4e38f;
  for (int n = lo+t; n < hi; n += 128) m = fmaxf(m, gate[n]);
  #pragma unroll
  for (int msk = 1; msk < 64; msk <<= 1) m = fmaxf(m, __shfl_xor(m, msk));
  if ((t & 63) == 0) red[t >> 6] = m;
  __syncthreads();
  m = fmaxf(red[0], red[1]);
  __syncthreads();
  float sl = 0.f;
  for (int n = lo+t; n < hi; n += 128) sl += __expf(gate[n]-m);
  #pragma unroll
  for (int msk = 1; msk < 64; msk <<= 1) sl += __shfl_xor(sl, msk);
  if ((t & 63) == 0) red[t >> 6] = sl;
  __syncthreads();
  float s = red[0] + red[1];
  float acc = 0.f;
  for (int n = lo; n < hi; ++n) {
    float w = __expf(gate[n]-m);
    acc += w * h2[(size_t)n*128 + t];
  }
  pld[t] = acc / (s + 1e-16f);
  __syncthreads();
  if (t < 32) {
    float z = fc1b[t];
    #pragma unroll 4
    for (int k = 0; k < 128; ++k) z += pld[k]*fc1W[k*32 + t];
    zs[t] = fmaxf(z, 0.f);
  }
  __syncthreads();
  if (t < 32) {
    float pv = zs[t]*valW[t];
    #pragma unroll
    for (int msk = 1; msk < 32; msk <<= 1) pv += __shfl_xor(pv, msk);
    if (t == 0) sval = pv + valb[0];
  }
  if (t < 16) {
    float a = advb[t];
    #pragma unroll
    for (int k = 0; k < 32; ++k) a += zs[k]*advW[k*16 + t];
    adv_s[t] = a;
  }
  __syncthreads();
  if (t < 16) {
    float amean = adv_s[t];
    #pragma unroll
    for (int msk = 1; msk < 16; msk <<= 1) amean += __shfl_xor(amean, msk);
    amean *= (1.f/16.f);
    out[g*16 + t] = sval + adv_s[t] - amean;
  }
}

extern "C" void kernel_launch(void* const* d_in, const int* in_sizes, int n_in,
                              void* d_out, int out_size, void* d_ws, size_t ws_size,
                              hipStream_t stream)
{
  const float* x     = (const float*)d_in[0];
  const int*   eidx  = (const int*)  d_in[1];
  const int*   batch = (const int*)  d_in[2];
  const float* W1    = (const float*)d_in[3];
  const float* as1w  = (const float*)d_in[4];
  const float* ad1w  = (const float*)d_in[5];
  const float* b1    = (const float*)d_in[6];
  const float* bn1g  = (const float*)d_in[7];
  const float* bn1b  = (const float*)d_in[8];
  const float* bn1rm = (const float*)d_in[9];
  const float* bn1rv = (const float*)d_in[10];
  const float* W2    = (const float*)d_in[11];
  const float* as2w  = (const float*)d_in[12];
  const float* ad2w  = (const float*)d_in[13];
  const float* b2    = (const float*)d_in[14];
  const float* bn2g  = (const float*)d_in[15];
  const float* bn2b  = (const float*)d_in[16];
  const float* bn2rm = (const float*)d_in[17];
  const float* bn2rv = (const float*)d_in[18];
  const float* gateW = (const float*)d_in[19];
  const float* gateB = (const float*)d_in[20];
  const float* fc1W  = (const float*)d_in[21];
  const float* fc1b  = (const float*)d_in[22];
  const float* valW  = (const float*)d_in[23];
  const float* valb  = (const float*)d_in[24];
  const float* advW  = (const float*)d_in[25];
  const float* advb  = (const float*)d_in[26];

  int N = in_sizes[0] / 32;
  int E = in_sizes[1] / 2;
  const int* esrc = eidx;
  const int* edst = eidx + E;

  float* ws = (float*)d_ws;
  size_t o = 0;
  __half* xh1h = (__half*)(ws + o); o += (size_t)N*32;   // N*64 halves
  __half* xh2h = (__half*)(ws + o); o += (size_t)N*64;   // N*128 halves
  float* as1 = ws + o; o += (size_t)N*4;
  float* ad1 = ws + o; o += (size_t)N*4;
  float* as2 = ws + o; o += (size_t)N*4;
  float* ad2 = ws + o; o += (size_t)N*4;
  float* h1  = ws + o; o += (size_t)N*64;
  float* h2  = ws + o; o += (size_t)N*128;
  float* gate = ws + o; o += (size_t)N;
  int* ib     = (int*)(ws + o);
  int* deg    = ib;                        // N
  int* cursor = ib + N;                    // N
  int* gcnt   = ib + 2*(size_t)N;          // NUM_G (deg..gcnt zeroed together)
  int* off    = ib + 2*(size_t)N + NUM_G;  // N+1
  int* goff   = off + (N+1);               // NUM_G+1
  int* csr    = goff + (NUM_G+1);          // E

  hipMemsetAsync(deg, 0, (size_t)(2*(size_t)N + NUM_G)*sizeof(int), stream);

  lin1_kernel<<<1024, 256, 0, stream>>>(x, W1, as1w, ad1w, xh1h, as1, ad1, N);
  hist_kernel<<<1024, 256, 0, stream>>>(edst, deg, E);
  hist_kernel<<<256, 256, 0, stream>>>(batch, gcnt, N);
  exscan2_kernel<<<2, 1024, 0, stream>>>(deg, off, N, gcnt, goff, NUM_G);
  scatter_kernel<<<1024, 256, 0, stream>>>(esrc, edst, off, cursor, csr, E);
  gat_agg1_kernel<<<2048, 256, 0, stream>>>(xh1h, as1, ad1, off, csr,
      b1, bn1g, bn1b, bn1rm, bn1rv, h1, N);
  lin2_kernel<<<1024, 256, 0, stream>>>(h1, W2, as2w, ad2w, xh2h, as2, ad2, N);
  gat_agg2_kernel<<<2048, 256, 0, stream>>>(xh2h, as2, ad2, off, csr,
      b2, bn2g, bn2b, bn2rm, bn2rv, gateW, gateB, h2, gate, N);
  pool_kernel<<<NUM_G, 128, 0, stream>>>(h2, gate, goff, fc1W, fc1b, valW, valb, advW, advb,
      (float*)d_out);
}

// Round 4
// 445.061 us; speedup vs baseline: 1.4587x; 1.0975x over previous
//
#include <hip/hip_runtime.h>
#include <hip/hip_fp16.h>
#include <math.h>

#define NEG_SLOPE 0.2f
#define BN_EPS_F 1e-5f
#define NUM_G 500
#define NBUK_MAX 128
#define CHUNK 4096

__device__ __forceinline__ float leaky(float x){ return x > 0.f ? x : NEG_SLOPE*x; }
__device__ __forceinline__ float bcast(float v, int k){
  return __int_as_float(__builtin_amdgcn_readlane(__float_as_int(v), k));
}

// ============ K1: fused histograms + lin1 (role split by blockIdx) ============
// roles: [0,HB): edge hist (deg + bucket counts); [HB,HB+BB): batch hist; rest: lin1
#define HB 512
#define BB 64
#define L1B 512
__global__ __launch_bounds__(256) void fused_hist_lin1_kernel(
    const int* __restrict__ edst, int E, int* __restrict__ deg, int* __restrict__ bukcnt,
    int bshift, int nbuk,
    const int* __restrict__ batch, int* __restrict__ gcnt,
    const float* __restrict__ x, const float* __restrict__ W,
    const float* __restrict__ att_s, const float* __restrict__ att_d,
    __half* __restrict__ xh, float* __restrict__ a_src, float* __restrict__ a_dst, int N)
{
  __shared__ int lhist[NUM_G];
  int t = threadIdx.x;
  int bid = blockIdx.x;
  if (bid < HB) {
    // edge histogram: per-node degree (global atomics) + per-bucket counts (LDS)
    if (t < NBUK_MAX) lhist[t] = 0;
    __syncthreads();
    int i = bid*256 + t, stride = HB*256;
    for (; i < E; i += stride) {
      int d = edst[i];
      atomicAdd(&deg[d], 1);
      atomicAdd(&lhist[d >> bshift], 1);
    }
    __syncthreads();
    if (t < nbuk && lhist[t]) atomicAdd(&bukcnt[t], lhist[t]);
  } else if (bid < HB + BB) {
    for (int i = t; i < NUM_G; i += 256) lhist[i] = 0;
    __syncthreads();
    int i = (bid-HB)*256 + t, stride = BB*256;
    for (; i < N; i += stride) atomicAdd(&lhist[batch[i]], 1);
    __syncthreads();
    for (int i = t; i < NUM_G; i += 256) if (lhist[i]) atomicAdd(&gcnt[i], lhist[i]);
  } else {
    int lane = t & 63;
    int wid  = ((bid - HB - BB)*256 + t) >> 6;
    int nw   = (L1B*256) >> 6;
    float w[32];
    #pragma unroll
    for (int k = 0; k < 32; ++k) w[k] = W[k*64 + lane];
    float asv = att_s[lane], adv = att_d[lane];
    for (int n = wid; n < N; n += nw) {
      float xv = (lane < 32) ? x[(size_t)n*32 + lane] : 0.f;
      float acc = 0.f;
      #pragma unroll
      for (int k = 0; k < 32; ++k) acc = fmaf(bcast(xv, k), w[k], acc);
      float sv = acc*asv, dv = acc*adv;
      #pragma unroll
      for (int m = 1; m < 16; m <<= 1) { sv += __shfl_xor(sv, m); dv += __shfl_xor(dv, m); }
      xh[(size_t)n*64 + lane] = __float2half(acc);
      if ((lane & 15) == 0) { a_src[n*4 + (lane>>4)] = sv; a_dst[n*4 + (lane>>4)] = dv; }
    }
  }
}

// ============ K2: three exclusive scans in one launch ============
__global__ __launch_bounds__(1024) void exscan3_kernel(
    const int* __restrict__ in0, int* __restrict__ out0, int n0,
    const int* __restrict__ in1, int* __restrict__ out1, int n1,
    const int* __restrict__ in2, int* __restrict__ out2, int n2)
{
  const int* in  = blockIdx.x==0 ? in0  : (blockIdx.x==1 ? in1  : in2);
  int*       out = blockIdx.x==0 ? out0 : (blockIdx.x==1 ? out1 : out2);
  int        n   = blockIdx.x==0 ? n0   : (blockIdx.x==1 ? n1   : n2);
  __shared__ int part[1024];
  int t = threadIdx.x;
  int per = (n + 1023) >> 10;
  int lo = t*per, hi = lo + per; if (lo > n) lo = n; if (hi > n) hi = n;
  int s = 0;
  for (int i = lo; i < hi; ++i) s += in[i];
  part[t] = s;
  __syncthreads();
  for (int ofs = 1; ofs < 1024; ofs <<= 1) {
    int v = (t >= ofs) ? part[t-ofs] : 0;
    __syncthreads();
    part[t] += v;
    __syncthreads();
  }
  int base = part[t] - s;
  for (int i = lo; i < hi; ++i) { out[i] = base; base += in[i]; }
  if (t == 1023) out[n] = part[1023];
}

// ============ K3: binned scatter (pass B) — LDS reorder by bucket, coalesced out ============
__global__ __launch_bounds__(256) void binscat_kernel(
    const int* __restrict__ esrc, const int* __restrict__ edst, int E,
    const int* __restrict__ bukoff, int* __restrict__ bukcur,
    int2* __restrict__ pairs, int bshift, int nbuk)
{
  __shared__ int hist[NBUK_MAX];
  __shared__ int loffs[NBUK_MAX];
  __shared__ int gbase[NBUK_MAX];
  __shared__ int2 stage[CHUNK];
  int t = threadIdx.x;
  for (int c0 = blockIdx.x*CHUNK; c0 < E; c0 += gridDim.x*CHUNK) {
    int cnt = E - c0; if (cnt > CHUNK) cnt = CHUNK;
    if (t < NBUK_MAX) hist[t] = 0;
    __syncthreads();
    for (int i = t; i < cnt; i += 256)
      atomicAdd(&hist[edst[c0+i] >> bshift], 1);
    __syncthreads();
    int cb = (t < nbuk) ? hist[t] : 0;
    // inclusive Hillis-Steele scan over nbuk entries
    for (int ofs = 1; ofs < nbuk; ofs <<= 1) {
      int v = (t < nbuk && t >= ofs) ? hist[t-ofs] : 0;
      __syncthreads();
      if (t < nbuk) hist[t] += v;
      __syncthreads();
    }
    if (t < nbuk) {
      int lo = hist[t] - cb;
      loffs[t] = lo;
      int base = atomicAdd(&bukcur[t], cb);
      gbase[t] = bukoff[t] + base - lo;
    }
    __syncthreads();
    if (t < nbuk) hist[t] = 0;   // reuse as rank cursor
    __syncthreads();
    for (int i = t; i < cnt; i += 256) {
      int s = esrc[c0+i], d = edst[c0+i];
      int b = d >> bshift;
      int r = atomicAdd(&hist[b], 1);
      stage[loffs[b] + r] = make_int2(s, d);
    }
    __syncthreads();
    for (int j = t; j < cnt; j += 256) {
      int2 p = stage[j];
      pairs[gbase[p.y >> bshift] + j] = p;
    }
    __syncthreads();
  }
}

// ============ K4: fine scatter (pass C) — per-bucket, L2-local ============
__global__ __launch_bounds__(256) void finescat_kernel(
    const int2* __restrict__ pairs, const int* __restrict__ bukoff,
    const int* __restrict__ off, int* __restrict__ cursor, int* __restrict__ csr)
{
  int b = blockIdx.x >> 2, part = blockIdx.x & 3;
  int lo = bukoff[b], hi = bukoff[b+1];
  for (int i = lo + part*256 + threadIdx.x; i < hi; i += 1024) {
    int2 p = pairs[i];
    int pos = off[p.y] + atomicAdd(&cursor[p.y], 1);
    csr[pos] = p.x;
  }
}

// ============ GAT agg layer 1 (F=64), unroll-8 fused pass ============
__global__ __launch_bounds__(256) void gat_agg1_kernel(
    const __half* __restrict__ xh, const float* __restrict__ a_src, const float* __restrict__ a_dst,
    const int* __restrict__ off, const int* __restrict__ csr,
    const float* __restrict__ bias, const float* __restrict__ bng, const float* __restrict__ bnb,
    const float* __restrict__ bnrm, const float* __restrict__ bnrv,
    float* __restrict__ hout, int N)
{
  int lane = threadIdx.x & 63;
  int wid  = (blockIdx.x * blockDim.x + threadIdx.x) >> 6;
  int nw   = (gridDim.x * blockDim.x) >> 6;
  int h = lane >> 4;
  float sc  = rsqrtf(bnrv[lane]+BN_EPS_F) * bng[lane];
  float ofc = bias[lane]*sc + bnb[lane] - bnrm[lane]*sc;
  for (int n = wid; n < N; n += nw) {
    int e = off[n], hi = off[n+1];
    float adh = a_dst[n*4+h];
    float es  = __expf(leaky(a_src[n*4+h] + adh));
    float acc = 0.f, ssum = 0.f;
    for (; e+7 < hi; e += 8) {
      int s0=csr[e],   s1=csr[e+1], s2=csr[e+2], s3=csr[e+3];
      int s4=csr[e+4], s5=csr[e+5], s6=csr[e+6], s7=csr[e+7];
      float a0=a_src[s0*4+h], a1=a_src[s1*4+h], a2=a_src[s2*4+h], a3=a_src[s3*4+h];
      float a4=a_src[s4*4+h], a5=a_src[s5*4+h], a6=a_src[s6*4+h], a7=a_src[s7*4+h];
      float v0=__half2float(xh[(size_t)s0*64+lane]);
      float v1=__half2float(xh[(size_t)s1*64+lane]);
      float v2=__half2float(xh[(size_t)s2*64+lane]);
      float v3=__half2float(xh[(size_t)s3*64+lane]);
      float v4=__half2float(xh[(size_t)s4*64+lane]);
      float v5=__half2float(xh[(size_t)s5*64+lane]);
      float v6=__half2float(xh[(size_t)s6*64+lane]);
      float v7=__half2float(xh[(size_t)s7*64+lane]);
      float w0=__expf(leaky(a0+adh)), w1=__expf(leaky(a1+adh));
      float w2=__expf(leaky(a2+adh)), w3=__expf(leaky(a3+adh));
      float w4=__expf(leaky(a4+adh)), w5=__expf(leaky(a5+adh));
      float w6=__expf(leaky(a6+adh)), w7=__expf(leaky(a7+adh));
      ssum += ((w0+w1)+(w2+w3)) + ((w4+w5)+(w6+w7));
      acc = fmaf(w0,v0,acc); acc = fmaf(w1,v1,acc);
      acc = fmaf(w2,v2,acc); acc = fmaf(w3,v3,acc);
      acc = fmaf(w4,v4,acc); acc = fmaf(w5,v5,acc);
      acc = fmaf(w6,v6,acc); acc = fmaf(w7,v7,acc);
    }
    for (; e < hi; ++e) {
      int s = csr[e];
      float a = a_src[s*4+h];
      float v = __half2float(xh[(size_t)s*64+lane]);
      float w = __expf(leaky(a+adh));
      ssum += w; acc = fmaf(w,v,acc);
    }
    float vs = __half2float(xh[(size_t)n*64+lane]);
    acc  = fmaf(es, vs, acc);
    ssum += es;
    float val = acc / (ssum + 1e-16f);
    hout[(size_t)n*64+lane] = fmaxf(fmaf(val, sc, ofc), 0.f);
  }
}

// ============ linear 2 ============
__global__ __launch_bounds__(256) void lin2_kernel(
    const float* __restrict__ hin, const float* __restrict__ W,
    const float* __restrict__ att_s, const float* __restrict__ att_d,
    __half* __restrict__ xh, float* __restrict__ a_src, float* __restrict__ a_dst, int N)
{
  int lane = threadIdx.x & 63;
  int wid  = (blockIdx.x * blockDim.x + threadIdx.x) >> 6;
  int nw   = (gridDim.x * blockDim.x) >> 6;
  float wa[64], wb[64];
  #pragma unroll
  for (int k = 0; k < 64; ++k) { wa[k] = W[k*128 + lane]; wb[k] = W[k*128 + 64 + lane]; }
  float asa = att_s[lane], ada = att_d[lane];
  float asb = att_s[64+lane], adb = att_d[64+lane];
  for (int n = wid; n < N; n += nw) {
    float hv = hin[(size_t)n*64 + lane];
    float a0 = 0.f, a1 = 0.f;
    #pragma unroll
    for (int k = 0; k < 64; ++k) {
      float h = bcast(hv, k);
      a0 = fmaf(h, wa[k], a0); a1 = fmaf(h, wb[k], a1);
    }
    float sva = a0*asa, dva = a0*ada, svb = a1*asb, dvb = a1*adb;
    #pragma unroll
    for (int m = 1; m < 32; m <<= 1) {
      sva += __shfl_xor(sva, m); dva += __shfl_xor(dva, m);
      svb += __shfl_xor(svb, m); dvb += __shfl_xor(dvb, m);
    }
    xh[(size_t)n*128 + lane] = __float2half(a0);
    xh[(size_t)n*128 + 64 + lane] = __float2half(a1);
    if ((lane & 31) == 0) {
      int hh = lane >> 5;
      a_src[n*4 + hh] = sva;     a_dst[n*4 + hh] = dva;
      a_src[n*4 + 2 + hh] = svb; a_dst[n*4 + 2 + hh] = dvb;
    }
  }
}

// ============ GAT agg layer 2 (F=128, half2), unroll-8, + pool gate ============
__global__ __launch_bounds__(256) void gat_agg2_kernel(
    const __half* __restrict__ xh, const float* __restrict__ a_src, const float* __restrict__ a_dst,
    const int* __restrict__ off, const int* __restrict__ csr,
    const float* __restrict__ bias, const float* __restrict__ bng, const float* __restrict__ bnb,
    const float* __restrict__ bnrm, const float* __restrict__ bnrv,
    const float* __restrict__ gateW, const float* __restrict__ gateB,
    float* __restrict__ hout, float* __restrict__ gate, int N)
{
  int lane = threadIdx.x & 63;
  int wid  = (blockIdx.x * blockDim.x + threadIdx.x) >> 6;
  int nw   = (gridDim.x * blockDim.x) >> 6;
  int c2 = 2*lane, h = lane >> 4;
  float sc0  = rsqrtf(bnrv[c2  ]+BN_EPS_F) * bng[c2  ];
  float of0  = bias[c2  ]*sc0 + bnb[c2  ] - bnrm[c2  ]*sc0;
  float sc1  = rsqrtf(bnrv[c2+1]+BN_EPS_F) * bng[c2+1];
  float of1  = bias[c2+1]*sc1 + bnb[c2+1] - bnrm[c2+1]*sc1;
  float gw0 = gateW[c2], gw1 = gateW[c2+1], gb = gateB[0];
  const __half2* xhv = (const __half2*)xh;   // row stride 64 half2
  for (int n = wid; n < N; n += nw) {
    int e = off[n], hi = off[n+1];
    float adh = a_dst[n*4+h];
    float es  = __expf(leaky(a_src[n*4+h] + adh));
    float accx = 0.f, accy = 0.f, ssum = 0.f;
    for (; e+7 < hi; e += 8) {
      int s0=csr[e],   s1=csr[e+1], s2=csr[e+2], s3=csr[e+3];
      int s4=csr[e+4], s5=csr[e+5], s6=csr[e+6], s7=csr[e+7];
      float a0=a_src[s0*4+h], a1=a_src[s1*4+h], a2=a_src[s2*4+h], a3=a_src[s3*4+h];
      float a4=a_src[s4*4+h], a5=a_src[s5*4+h], a6=a_src[s6*4+h], a7=a_src[s7*4+h];
      __half2 v0 = xhv[(size_t)s0*64 + lane];
      __half2 v1 = xhv[(size_t)s1*64 + lane];
      __half2 v2 = xhv[(size_t)s2*64 + lane];
      __half2 v3 = xhv[(size_t)s3*64 + lane];
      __half2 v4 = xhv[(size_t)s4*64 + lane];
      __half2 v5 = xhv[(size_t)s5*64 + lane];
      __half2 v6 = xhv[(size_t)s6*64 + lane];
      __half2 v7 = xhv[(size_t)s7*64 + lane];
      float w0=__expf(leaky(a0+adh)), w1=__expf(leaky(a1+adh));
      float w2=__expf(leaky(a2+adh)), w3=__expf(leaky(a3+adh));
      float w4=__expf(leaky(a4+adh)), w5=__expf(leaky(a5+adh));
      float w6=__expf(leaky(a6+adh)), w7=__expf(leaky(a7+adh));
      ssum += ((w0+w1)+(w2+w3)) + ((w4+w5)+(w6+w7));
      float2 f0=__half22float2(v0), f1=__half22float2(v1);
      float2 f2=__half22float2(v2), f3=__half22float2(v3);
      float2 f4=__half22float2(v4), f5=__half22float2(v5);
      float2 f6=__half22float2(v6), f7=__half22float2(v7);
      accx = fmaf(w0,f0.x,accx); accy = fmaf(w0,f0.y,accy);
      accx = fmaf(w1,f1.x,accx); accy = fmaf(w1,f1.y,accy);
      accx = fmaf(w2,f2.x,accx); accy = fmaf(w2,f2.y,accy);
      accx = fmaf(w3,f3.x,accx); accy = fmaf(w3,f3.y,accy);
      accx = fmaf(w4,f4.x,accx); accy = fmaf(w4,f4.y,accy);
      accx = fmaf(w5,f5.x,accx); accy = fmaf(w5,f5.y,accy);
      accx = fmaf(w6,f6.x,accx); accy = fmaf(w6,f6.y,accy);
      accx = fmaf(w7,f7.x,accx); accy = fmaf(w7,f7.y,accy);
    }
    for (; e < hi; ++e) {
      int s = csr[e];
      float a = a_src[s*4+h];
      __half2 v = xhv[(size_t)s*64 + lane];
      float w = __expf(leaky(a+adh));
      float2 f = __half22float2(v);
      ssum += w; accx = fmaf(w,f.x,accx); accy = fmaf(w,f.y,accy);
    }
    float2 fs = __half22float2(xhv[(size_t)n*64 + lane]);
    accx = fmaf(es, fs.x, accx); accy = fmaf(es, fs.y, accy);
    ssum += es;
    float inv = 1.f / (ssum + 1e-16f);
    float r0 = fmaxf(fmaf(accx*inv, sc0, of0), 0.f);
    float r1 = fmaxf(fmaf(accy*inv, sc1, of1), 0.f);
    *(float2*)(hout + (size_t)n*128 + c2) = make_float2(r0, r1);
    float gl = r0*gw0 + r1*gw1;
    #pragma unroll
    for (int m = 1; m < 64; m <<= 1) gl += __shfl_xor(gl, m);
    if (lane == 0) gate[n] = gl + gb;
  }
}

// ============ per-graph attention pooling + MLP heads ============
__global__ __launch_bounds__(128) void pool_kernel(
    const float* __restrict__ h2, const float* __restrict__ gate, const int* __restrict__ goff,
    const float* __restrict__ fc1W, const float* __restrict__ fc1b,
    const float* __restrict__ valW, const float* __restrict__ valb,
    const float* __restrict__ advW, const float* __restrict__ advb,
    float* __restrict__ out)
{
  int g = blockIdx.x, t = threadIdx.x;
  int lo = goff[g], hi = goff[g+1];
  __shared__ float red[2];
  __shared__ float pld[128];
  __shared__ float zs[32];
  __shared__ float sval;
  __shared__ float adv_s[16];

  float m = -3.4e38f;
  for (int n = lo+t; n < hi; n += 128) m = fmaxf(m, gate[n]);
  #pragma unroll
  for (int msk = 1; msk < 64; msk <<= 1) m = fmaxf(m, __shfl_xor(m, msk));
  if ((t & 63) == 0) red[t >> 6] = m;
  __syncthreads();
  m = fmaxf(red[0], red[1]);
  __syncthreads();
  float sl = 0.f;
  for (int n = lo+t; n < hi; n += 128) sl += __expf(gate[n]-m);
  #pragma unroll
  for (int msk = 1; msk < 64; msk <<= 1) sl += __shfl_xor(sl, msk);
  if ((t & 63) == 0) red[t >> 6] = sl;
  __syncthreads();
  float s = red[0] + red[1];
  float acc = 0.f;
  for (int n = lo; n < hi; ++n) {
    float w = __expf(gate[n]-m);
    acc += w * h2[(size_t)n*128 + t];
  }
  pld[t] = acc / (s + 1e-16f);
  __syncthreads();
  if (t < 32) {
    float z = fc1b[t];
    #pragma unroll 4
    for (int k = 0; k < 128; ++k) z += pld[k]*fc1W[k*32 + t];
    zs[t] = fmaxf(z, 0.f);
  }
  __syncthreads();
  if (t < 32) {
    float pv = zs[t]*valW[t];
    #pragma unroll
    for (int msk = 1; msk < 32; msk <<= 1) pv += __shfl_xor(pv, msk);
    if (t == 0) sval = pv + valb[0];
  }
  if (t < 16) {
    float a = advb[t];
    #pragma unroll
    for (int k = 0; k < 32; ++k) a += zs[k]*advW[k*16 + t];
    adv_s[t] = a;
  }
  __syncthreads();
  if (t < 16) {
    float amean = adv_s[t];
    #pragma unroll
    for (int msk = 1; msk < 16; msk <<= 1) amean += __shfl_xor(amean, msk);
    amean *= (1.f/16.f);
    out[g*16 + t] = sval + adv_s[t] - amean;
  }
}

extern "C" void kernel_launch(void* const* d_in, const int* in_sizes, int n_in,
                              void* d_out, int out_size, void* d_ws, size_t ws_size,
                              hipStream_t stream)
{
  const float* x     = (const float*)d_in[0];
  const int*   eidx  = (const int*)  d_in[1];
  const int*   batch = (const int*)  d_in[2];
  const float* W1    = (const float*)d_in[3];
  const float* as1w  = (const float*)d_in[4];
  const float* ad1w  = (const float*)d_in[5];
  const float* b1    = (const float*)d_in[6];
  const float* bn1g  = (const float*)d_in[7];
  const float* bn1b  = (const float*)d_in[8];
  const float* bn1rm = (const float*)d_in[9];
  const float* bn1rv = (const float*)d_in[10];
  const float* W2    = (const float*)d_in[11];
  const float* as2w  = (const float*)d_in[12];
  const float* ad2w  = (const float*)d_in[13];
  const float* b2    = (const float*)d_in[14];
  const float* bn2g  = (const float*)d_in[15];
  const float* bn2b  = (const float*)d_in[16];
  const float* bn2rm = (const float*)d_in[17];
  const float* bn2rv = (const float*)d_in[18];
  const float* gateW = (const float*)d_in[19];
  const float* gateB = (const float*)d_in[20];
  const float* fc1W  = (const float*)d_in[21];
  const float* fc1b  = (const float*)d_in[22];
  const float* valW  = (const float*)d_in[23];
  const float* valb  = (const float*)d_in[24];
  const float* advW  = (const float*)d_in[25];
  const float* advb  = (const float*)d_in[26];

  int N = in_sizes[0] / 32;
  int E = in_sizes[1] / 2;
  const int* esrc = eidx;
  const int* edst = eidx + E;

  // bucket shift: NBUK = ceil(N/2^bshift) <= NBUK_MAX
  int bshift = 9;
  while ((((N - 1) >> bshift) + 1) > NBUK_MAX) ++bshift;
  int nbuk = ((N - 1) >> bshift) + 1;

  float* ws = (float*)d_ws;
  size_t o = 0;
  __half* xh1h = (__half*)(ws + o); o += (size_t)N*32;   // N*64 halves
  __half* xh2h = (__half*)(ws + o); o += (size_t)N*64;   // N*128 halves
  float* as1 = ws + o; o += (size_t)N*4;
  float* ad1 = ws + o; o += (size_t)N*4;
  float* as2 = ws + o; o += (size_t)N*4;
  float* ad2 = ws + o; o += (size_t)N*4;
  float* h1  = ws + o; o += (size_t)N*64;
  float* h2  = ws + o; o += (size_t)N*128;
  float* gate = ws + o; o += (size_t)N;
  if (o & 1) ++o;                                  // 8B align for int2
  int2* pairs = (int2*)(ws + o); o += (size_t)E*2;
  int* ib     = (int*)(ws + o);
  // zeroed block: deg[N], gcnt[512], bukcnt[128], bukcur[128], cursor[N]
  int* deg    = ib;
  int* gcnt   = ib + N;
  int* bukcnt = ib + N + 512;
  int* bukcur = ib + N + 640;
  int* cursor = ib + N + 768;
  size_t zcnt = (size_t)2*N + 768;
  // non-zeroed:
  int* off    = ib + zcnt;                 // N+1
  int* goff   = off + (N+1);               // NUM_G+1
  int* bukoff = goff + (NUM_G+1);          // nbuk+1
  int* csr    = bukoff + (NBUK_MAX+1);     // E

  hipMemsetAsync(deg, 0, zcnt*sizeof(int), stream);

  fused_hist_lin1_kernel<<<HB+BB+L1B, 256, 0, stream>>>(
      edst, E, deg, bukcnt, bshift, nbuk, batch, gcnt,
      x, W1, as1w, ad1w, xh1h, as1, ad1, N);
  exscan3_kernel<<<3, 1024, 0, stream>>>(deg, off, N, gcnt, goff, NUM_G, bukcnt, bukoff, nbuk);
  int nchunk = (E + CHUNK - 1) / CHUNK;
  binscat_kernel<<<nchunk, 256, 0, stream>>>(esrc, edst, E, bukoff, bukcur, pairs, bshift, nbuk);
  finescat_kernel<<<nbuk*4, 256, 0, stream>>>(pairs, bukoff, off, cursor, csr);
  gat_agg1_kernel<<<2048, 256, 0, stream>>>(xh1h, as1, ad1, off, csr,
      b1, bn1g, bn1b, bn1rm, bn1rv, h1, N);
  lin2_kernel<<<1024, 256, 0, stream>>>(h1, W2, as2w, ad2w, xh2h, as2, ad2, N);
  gat_agg2_kernel<<<2048, 256, 0, stream>>>(xh2h, as2, ad2, off, csr,
      b2, bn2g, bn2b, bn2rm, bn2rv, gateW, gateB, h2, gate, N);
  pool_kernel<<<NUM_G, 128, 0, stream>>>(h2, gate, goff, fc1W, fc1b, valW, valb, advW, advb,
      (float*)d_out);
}

// Round 5
// 291.098 us; speedup vs baseline: 2.2303x; 1.5289x over previous
//
#include <hip/hip_runtime.h>
#include <hip/hip_fp16.h>
#include <math.h>

#define NEG_SLOPE 0.2f
#define BN_EPS_F 1e-5f
#define NUM_G 500
#define NBUK_MAX 128
#define CHUNK 4096

__device__ __forceinline__ float leaky(float x){ return x > 0.f ? x : NEG_SLOPE*x; }
__device__ __forceinline__ float bcast(float v, int k){
  return __int_as_float(__builtin_amdgcn_readlane(__float_as_int(v), k));
}

// ============ K1: fused bucket-hist + batch-hist + lin1 (role split by blockIdx) ============
#define HB 256
#define BB 64
#define L1B 512
__global__ __launch_bounds__(256) void fused_hist_lin1_kernel(
    const int* __restrict__ edst, int E, int* __restrict__ bukcnt,
    int bshift, int nbuk,
    const int* __restrict__ batch, int* __restrict__ gcnt,
    const float* __restrict__ x, const float* __restrict__ W,
    const float* __restrict__ att_s, const float* __restrict__ att_d,
    __half* __restrict__ xh, float* __restrict__ a_src, float* __restrict__ a_dst, int N)
{
  __shared__ int lhist[NUM_G];
  int t = threadIdx.x;
  int bid = blockIdx.x;
  if (bid < HB) {
    // edge bucket histogram only (no per-node atomics!)
    if (t < NBUK_MAX) lhist[t] = 0;
    __syncthreads();
    int i = bid*256 + t, stride = HB*256;
    for (; i < E; i += stride) atomicAdd(&lhist[edst[i] >> bshift], 1);
    __syncthreads();
    if (t < nbuk && lhist[t]) atomicAdd(&bukcnt[t], lhist[t]);
  } else if (bid < HB + BB) {
    for (int i = t; i < NUM_G; i += 256) lhist[i] = 0;
    __syncthreads();
    int i = (bid-HB)*256 + t, stride = BB*256;
    for (; i < N; i += stride) atomicAdd(&lhist[batch[i]], 1);
    __syncthreads();
    for (int i = t; i < NUM_G; i += 256) if (lhist[i]) atomicAdd(&gcnt[i], lhist[i]);
  } else {
    int lane = t & 63;
    int wid  = ((bid - HB - BB)*256 + t) >> 6;
    int nw   = (L1B*256) >> 6;
    float w[32];
    #pragma unroll
    for (int k = 0; k < 32; ++k) w[k] = W[k*64 + lane];
    float asv = att_s[lane], adv = att_d[lane];
    for (int n = wid; n < N; n += nw) {
      float xv = (lane < 32) ? x[(size_t)n*32 + lane] : 0.f;
      float acc = 0.f;
      #pragma unroll
      for (int k = 0; k < 32; ++k) acc = fmaf(bcast(xv, k), w[k], acc);
      float sv = acc*asv, dv = acc*adv;
      #pragma unroll
      for (int m = 1; m < 16; m <<= 1) { sv += __shfl_xor(sv, m); dv += __shfl_xor(dv, m); }
      xh[(size_t)n*64 + lane] = __float2half(acc);
      if ((lane & 15) == 0) { a_src[n*4 + (lane>>4)] = sv; a_dst[n*4 + (lane>>4)] = dv; }
    }
  }
}

// ============ K2: two exclusive scans in one launch (both tiny) ============
__global__ __launch_bounds__(1024) void exscan2_kernel(
    const int* __restrict__ in0, int* __restrict__ out0, int n0,
    const int* __restrict__ in1, int* __restrict__ out1, int n1)
{
  const int* in  = blockIdx.x ? in1  : in0;
  int*       out = blockIdx.x ? out1 : out0;
  int        n   = blockIdx.x ? n1   : n0;
  __shared__ int part[1024];
  int t = threadIdx.x;
  int per = (n + 1023) >> 10;
  int lo = t*per, hi = lo + per; if (lo > n) lo = n; if (hi > n) hi = n;
  int s = 0;
  for (int i = lo; i < hi; ++i) s += in[i];
  part[t] = s;
  __syncthreads();
  for (int ofs = 1; ofs < 1024; ofs <<= 1) {
    int v = (t >= ofs) ? part[t-ofs] : 0;
    __syncthreads();
    part[t] += v;
    __syncthreads();
  }
  int base = part[t] - s;
  for (int i = lo; i < hi; ++i) { out[i] = base; base += in[i]; }
  if (t == 1023) out[n] = part[1023];
}

// ============ K3: binned scatter (pass B) — LDS reorder by bucket, coalesced out ============
__global__ __launch_bounds__(256) void binscat_kernel(
    const int* __restrict__ esrc, const int* __restrict__ edst, int E,
    const int* __restrict__ bukoff, int* __restrict__ bukcur,
    int2* __restrict__ pairs, int bshift, int nbuk)
{
  __shared__ int hist[NBUK_MAX];
  __shared__ int loffs[NBUK_MAX];
  __shared__ int gbase[NBUK_MAX];
  __shared__ int2 stage[CHUNK];
  int t = threadIdx.x;
  for (int c0 = blockIdx.x*CHUNK; c0 < E; c0 += gridDim.x*CHUNK) {
    int cnt = E - c0; if (cnt > CHUNK) cnt = CHUNK;
    if (t < NBUK_MAX) hist[t] = 0;
    __syncthreads();
    for (int i = t; i < cnt; i += 256)
      atomicAdd(&hist[edst[c0+i] >> bshift], 1);
    __syncthreads();
    int cb = (t < nbuk) ? hist[t] : 0;
    for (int ofs = 1; ofs < nbuk; ofs <<= 1) {
      int v = (t < nbuk && t >= ofs) ? hist[t-ofs] : 0;
      __syncthreads();
      if (t < nbuk) hist[t] += v;
      __syncthreads();
    }
    if (t < nbuk) {
      int lo = hist[t] - cb;
      loffs[t] = lo;
      int base = atomicAdd(&bukcur[t], cb);
      gbase[t] = bukoff[t] + base - lo;
    }
    __syncthreads();
    if (t < nbuk) hist[t] = 0;   // reuse as rank cursor
    __syncthreads();
    for (int i = t; i < cnt; i += 256) {
      int s = esrc[c0+i], d = edst[c0+i];
      int b = d >> bshift;
      int r = atomicAdd(&hist[b], 1);
      stage[loffs[b] + r] = make_int2(s, d);
    }
    __syncthreads();
    for (int j = t; j < cnt; j += 256) {
      int2 p = stage[j];
      pairs[gbase[p.y >> bshift] + j] = p;
    }
    __syncthreads();
  }
}

// ============ K4: per-bucket CSR build — LDS deg hist + scan -> off[], then local scatter ============
// One block per bucket. All per-node state lives in LDS; csr writes stay in the bucket's
// L2-local span. Also writes off[] (so no N-wide exscan / global deg / cursor needed).
__global__ __launch_bounds__(512) void bucket_csr_kernel(
    const int2* __restrict__ pairs, const int* __restrict__ bukoff,
    int* __restrict__ off, int* __restrict__ csr, int N, int E, int bshift)
{
  __shared__ int cnt[1024];
  __shared__ int cur[1024];
  __shared__ int part[512];
  int b = blockIdx.x, t = threadIdx.x;
  int base = b << bshift;
  int bnodes = 1 << bshift;            // >= 512 by construction
  int nlocal = N - base; if (nlocal > bnodes) nlocal = bnodes;
  int lo = bukoff[b], hi = bukoff[b+1];
  int gb = lo;
  for (int i = t; i < bnodes; i += 512) cnt[i] = 0;
  __syncthreads();
  for (int i = lo + t; i < hi; i += 512) atomicAdd(&cnt[pairs[i].y - base], 1);
  __syncthreads();
  // exclusive scan of cnt[0..bnodes): per-thread chunk + block scan
  int Wc = bnodes >> 9;                // entries per thread (1 or 2)
  int mys = 0;
  for (int j = 0; j < Wc; ++j) mys += cnt[t*Wc + j];
  part[t] = mys;
  __syncthreads();
  for (int ofs = 1; ofs < 512; ofs <<= 1) {
    int v = (t >= ofs) ? part[t-ofs] : 0;
    __syncthreads();
    part[t] += v;
    __syncthreads();
  }
  int ex = part[t] - mys;
  for (int j = 0; j < Wc; ++j) { int c = cnt[t*Wc + j]; cnt[t*Wc + j] = ex; ex += c; }
  __syncthreads();
  // write off[] for this bucket (coalesced)
  for (int i = t; i < nlocal; i += 512) off[base + i] = gb + cnt[i];
  if (b == 0 && t == 0) off[N] = E;
  for (int i = t; i < bnodes; i += 512) cur[i] = 0;
  __syncthreads();
  // local scatter into csr (bucket span is L2-resident)
  for (int i = lo + t; i < hi; i += 512) {
    int2 p = pairs[i];
    int l = p.y - base;
    int pos = gb + cnt[l] + atomicAdd(&cur[l], 1);
    csr[pos] = p.x;
  }
}

// ============ GAT agg layer 1 (F=64), unroll-8 fused pass ============
__global__ __launch_bounds__(256) void gat_agg1_kernel(
    const __half* __restrict__ xh, const float* __restrict__ a_src, const float* __restrict__ a_dst,
    const int* __restrict__ off, const int* __restrict__ csr,
    const float* __restrict__ bias, const float* __restrict__ bng, const float* __restrict__ bnb,
    const float* __restrict__ bnrm, const float* __restrict__ bnrv,
    float* __restrict__ hout, int N)
{
  int lane = threadIdx.x & 63;
  int wid  = (blockIdx.x * blockDim.x + threadIdx.x) >> 6;
  int nw   = (gridDim.x * blockDim.x) >> 6;
  int h = lane >> 4;
  float sc  = rsqrtf(bnrv[lane]+BN_EPS_F) * bng[lane];
  float ofc = bias[lane]*sc + bnb[lane] - bnrm[lane]*sc;
  for (int n = wid; n < N; n += nw) {
    int e = off[n], hi = off[n+1];
    float adh = a_dst[n*4+h];
    float es  = __expf(leaky(a_src[n*4+h] + adh));
    float acc = 0.f, ssum = 0.f;
    for (; e+7 < hi; e += 8) {
      int s0=csr[e],   s1=csr[e+1], s2=csr[e+2], s3=csr[e+3];
      int s4=csr[e+4], s5=csr[e+5], s6=csr[e+6], s7=csr[e+7];
      float a0=a_src[s0*4+h], a1=a_src[s1*4+h], a2=a_src[s2*4+h], a3=a_src[s3*4+h];
      float a4=a_src[s4*4+h], a5=a_src[s5*4+h], a6=a_src[s6*4+h], a7=a_src[s7*4+h];
      float v0=__half2float(xh[(size_t)s0*64+lane]);
      float v1=__half2float(xh[(size_t)s1*64+lane]);
      float v2=__half2float(xh[(size_t)s2*64+lane]);
      float v3=__half2float(xh[(size_t)s3*64+lane]);
      float v4=__half2float(xh[(size_t)s4*64+lane]);
      float v5=__half2float(xh[(size_t)s5*64+lane]);
      float v6=__half2float(xh[(size_t)s6*64+lane]);
      float v7=__half2float(xh[(size_t)s7*64+lane]);
      float w0=__expf(leaky(a0+adh)), w1=__expf(leaky(a1+adh));
      float w2=__expf(leaky(a2+adh)), w3=__expf(leaky(a3+adh));
      float w4=__expf(leaky(a4+adh)), w5=__expf(leaky(a5+adh));
      float w6=__expf(leaky(a6+adh)), w7=__expf(leaky(a7+adh));
      ssum += ((w0+w1)+(w2+w3)) + ((w4+w5)+(w6+w7));
      acc = fmaf(w0,v0,acc); acc = fmaf(w1,v1,acc);
      acc = fmaf(w2,v2,acc); acc = fmaf(w3,v3,acc);
      acc = fmaf(w4,v4,acc); acc = fmaf(w5,v5,acc);
      acc = fmaf(w6,v6,acc); acc = fmaf(w7,v7,acc);
    }
    for (; e < hi; ++e) {
      int s = csr[e];
      float a = a_src[s*4+h];
      float v = __half2float(xh[(size_t)s*64+lane]);
      float w = __expf(leaky(a+adh));
      ssum += w; acc = fmaf(w,v,acc);
    }
    float vs = __half2float(xh[(size_t)n*64+lane]);
    acc  = fmaf(es, vs, acc);
    ssum += es;
    float val = acc / (ssum + 1e-16f);
    hout[(size_t)n*64+lane] = fmaxf(fmaf(val, sc, ofc), 0.f);
  }
}

// ============ linear 2 ============
__global__ __launch_bounds__(256) void lin2_kernel(
    const float* __restrict__ hin, const float* __restrict__ W,
    const float* __restrict__ att_s, const float* __restrict__ att_d,
    __half* __restrict__ xh, float* __restrict__ a_src, float* __restrict__ a_dst, int N)
{
  int lane = threadIdx.x & 63;
  int wid  = (blockIdx.x * blockDim.x + threadIdx.x) >> 6;
  int nw   = (gridDim.x * blockDim.x) >> 6;
  float wa[64], wb[64];
  #pragma unroll
  for (int k = 0; k < 64; ++k) { wa[k] = W[k*128 + lane]; wb[k] = W[k*128 + 64 + lane]; }
  float asa = att_s[lane], ada = att_d[lane];
  float asb = att_s[64+lane], adb = att_d[64+lane];
  for (int n = wid; n < N; n += nw) {
    float hv = hin[(size_t)n*64 + lane];
    float a0 = 0.f, a1 = 0.f;
    #pragma unroll
    for (int k = 0; k < 64; ++k) {
      float h = bcast(hv, k);
      a0 = fmaf(h, wa[k], a0); a1 = fmaf(h, wb[k], a1);
    }
    float sva = a0*asa, dva = a0*ada, svb = a1*asb, dvb = a1*adb;
    #pragma unroll
    for (int m = 1; m < 32; m <<= 1) {
      sva += __shfl_xor(sva, m); dva += __shfl_xor(dva, m);
      svb += __shfl_xor(svb, m); dvb += __shfl_xor(dvb, m);
    }
    xh[(size_t)n*128 + lane] = __float2half(a0);
    xh[(size_t)n*128 + 64 + lane] = __float2half(a1);
    if ((lane & 31) == 0) {
      int hh = lane >> 5;
      a_src[n*4 + hh] = sva;     a_dst[n*4 + hh] = dva;
      a_src[n*4 + 2 + hh] = svb; a_dst[n*4 + 2 + hh] = dvb;
    }
  }
}

// ============ GAT agg layer 2 (F=128, half2), unroll-8, + pool gate ============
__global__ __launch_bounds__(256) void gat_agg2_kernel(
    const __half* __restrict__ xh, const float* __restrict__ a_src, const float* __restrict__ a_dst,
    const int* __restrict__ off, const int* __restrict__ csr,
    const float* __restrict__ bias, const float* __restrict__ bng, const float* __restrict__ bnb,
    const float* __restrict__ bnrm, const float* __restrict__ bnrv,
    const float* __restrict__ gateW, const float* __restrict__ gateB,
    float* __restrict__ hout, float* __restrict__ gate, int N)
{
  int lane = threadIdx.x & 63;
  int wid  = (blockIdx.x * blockDim.x + threadIdx.x) >> 6;
  int nw   = (gridDim.x * blockDim.x) >> 6;
  int c2 = 2*lane, h = lane >> 4;
  float sc0  = rsqrtf(bnrv[c2  ]+BN_EPS_F) * bng[c2  ];
  float of0  = bias[c2  ]*sc0 + bnb[c2  ] - bnrm[c2  ]*sc0;
  float sc1  = rsqrtf(bnrv[c2+1]+BN_EPS_F) * bng[c2+1];
  float of1  = bias[c2+1]*sc1 + bnb[c2+1] - bnrm[c2+1]*sc1;
  float gw0 = gateW[c2], gw1 = gateW[c2+1], gb = gateB[0];
  const __half2* xhv = (const __half2*)xh;   // row stride 64 half2
  for (int n = wid; n < N; n += nw) {
    int e = off[n], hi = off[n+1];
    float adh = a_dst[n*4+h];
    float es  = __expf(leaky(a_src[n*4+h] + adh));
    float accx = 0.f, accy = 0.f, ssum = 0.f;
    for (; e+7 < hi; e += 8) {
      int s0=csr[e],   s1=csr[e+1], s2=csr[e+2], s3=csr[e+3];
      int s4=csr[e+4], s5=csr[e+5], s6=csr[e+6], s7=csr[e+7];
      float a0=a_src[s0*4+h], a1=a_src[s1*4+h], a2=a_src[s2*4+h], a3=a_src[s3*4+h];
      float a4=a_src[s4*4+h], a5=a_src[s5*4+h], a6=a_src[s6*4+h], a7=a_src[s7*4+h];
      __half2 v0 = xhv[(size_t)s0*64 + lane];
      __half2 v1 = xhv[(size_t)s1*64 + lane];
      __half2 v2 = xhv[(size_t)s2*64 + lane];
      __half2 v3 = xhv[(size_t)s3*64 + lane];
      __half2 v4 = xhv[(size_t)s4*64 + lane];
      __half2 v5 = xhv[(size_t)s5*64 + lane];
      __half2 v6 = xhv[(size_t)s6*64 + lane];
      __half2 v7 = xhv[(size_t)s7*64 + lane];
      float w0=__expf(leaky(a0+adh)), w1=__expf(leaky(a1+adh));
      float w2=__expf(leaky(a2+adh)), w3=__expf(leaky(a3+adh));
      float w4=__expf(leaky(a4+adh)), w5=__expf(leaky(a5+adh));
      float w6=__expf(leaky(a6+adh)), w7=__expf(leaky(a7+adh));
      ssum += ((w0+w1)+(w2+w3)) + ((w4+w5)+(w6+w7));
      float2 f0=__half22float2(v0), f1=__half22float2(v1);
      float2 f2=__half22float2(v2), f3=__half22float2(v3);
      float2 f4=__half22float2(v4), f5=__half22float2(v5);
      float2 f6=__half22float2(v6), f7=__half22float2(v7);
      accx = fmaf(w0,f0.x,accx); accy = fmaf(w0,f0.y,accy);
      accx = fmaf(w1,f1.x,accx); accy = fmaf(w1,f1.y,accy);
      accx = fmaf(w2,f2.x,accx); accy = fmaf(w2,f2.y,accy);
      accx = fmaf(w3,f3.x,accx); accy = fmaf(w3,f3.y,accy);
      accx = fmaf(w4,f4.x,accx); accy = fmaf(w4,f4.y,accy);
      accx = fmaf(w5,f5.x,accx); accy = fmaf(w5,f5.y,accy);
      accx = fmaf(w6,f6.x,accx); accy = fmaf(w6,f6.y,accy);
      accx = fmaf(w7,f7.x,accx); accy = fmaf(w7,f7.y,accy);
    }
    for (; e < hi; ++e) {
      int s = csr[e];
      float a = a_src[s*4+h];
      __half2 v = xhv[(size_t)s*64 + lane];
      float w = __expf(leaky(a+adh));
      float2 f = __half22float2(v);
      ssum += w; accx = fmaf(w,f.x,accx); accy = fmaf(w,f.y,accy);
    }
    float2 fs = __half22float2(xhv[(size_t)n*64 + lane]);
    accx = fmaf(es, fs.x, accx); accy = fmaf(es, fs.y, accy);
    ssum += es;
    float inv = 1.f / (ssum + 1e-16f);
    float r0 = fmaxf(fmaf(accx*inv, sc0, of0), 0.f);
    float r1 = fmaxf(fmaf(accy*inv, sc1, of1), 0.f);
    *(float2*)(hout + (size_t)n*128 + c2) = make_float2(r0, r1);
    float gl = r0*gw0 + r1*gw1;
    #pragma unroll
    for (int m = 1; m < 64; m <<= 1) gl += __shfl_xor(gl, m);
    if (lane == 0) gate[n] = gl + gb;
  }
}

// ============ per-graph attention pooling + MLP heads ============
__global__ __launch_bounds__(128) void pool_kernel(
    const float* __restrict__ h2, const float* __restrict__ gate, const int* __restrict__ goff,
    const float* __restrict__ fc1W, const float* __restrict__ fc1b,
    const float* __restrict__ valW, const float* __restrict__ valb,
    const float* __restrict__ advW, const float* __restrict__ advb,
    float* __restrict__ out)
{
  int g = blockIdx.x, t = threadIdx.x;
  int lo = goff[g], hi = goff[g+1];
  __shared__ float red[2];
  __shared__ float pld[128];
  __shared__ float zs[32];
  __shared__ float sval;
  __shared__ float adv_s[16];

  float m = -3.4e38f;
  for (int n = lo+t; n < hi; n += 128) m = fmaxf(m, gate[n]);
  #pragma unroll
  for (int msk = 1; msk < 64; msk <<= 1) m = fmaxf(m, __shfl_xor(m, msk));
  if ((t & 63) == 0) red[t >> 6] = m;
  __syncthreads();
  m = fmaxf(red[0], red[1]);
  __syncthreads();
  float sl = 0.f;
  for (int n = lo+t; n < hi; n += 128) sl += __expf(gate[n]-m);
  #pragma unroll
  for (int msk = 1; msk < 64; msk <<= 1) sl += __shfl_xor(sl, msk);
  if ((t & 63) == 0) red[t >> 6] = sl;
  __syncthreads();
  float s = red[0] + red[1];
  float acc = 0.f;
  for (int n = lo; n < hi; ++n) {
    float w = __expf(gate[n]-m);
    acc += w * h2[(size_t)n*128 + t];
  }
  pld[t] = acc / (s + 1e-16f);
  __syncthreads();
  if (t < 32) {
    float z = fc1b[t];
    #pragma unroll 4
    for (int k = 0; k < 128; ++k) z += pld[k]*fc1W[k*32 + t];
    zs[t] = fmaxf(z, 0.f);
  }
  __syncthreads();
  if (t < 32) {
    float pv = zs[t]*valW[t];
    #pragma unroll
    for (int msk = 1; msk < 32; msk <<= 1) pv += __shfl_xor(pv, msk);
    if (t == 0) sval = pv + valb[0];
  }
  if (t < 16) {
    float a = advb[t];
    #pragma unroll
    for (int k = 0; k < 32; ++k) a += zs[k]*advW[k*16 + t];
    adv_s[t] = a;
  }
  __syncthreads();
  if (t < 16) {
    float amean = adv_s[t];
    #pragma unroll
    for (int msk = 1; msk < 16; msk <<= 1) amean += __shfl_xor(amean, msk);
    amean *= (1.f/16.f);
    out[g*16 + t] = sval + adv_s[t] - amean;
  }
}

extern "C" void kernel_launch(void* const* d_in, const int* in_sizes, int n_in,
                              void* d_out, int out_size, void* d_ws, size_t ws_size,
                              hipStream_t stream)
{
  const float* x     = (const float*)d_in[0];
  const int*   eidx  = (const int*)  d_in[1];
  const int*   batch = (const int*)  d_in[2];
  const float* W1    = (const float*)d_in[3];
  const float* as1w  = (const float*)d_in[4];
  const float* ad1w  = (const float*)d_in[5];
  const float* b1    = (const float*)d_in[6];
  const float* bn1g  = (const float*)d_in[7];
  const float* bn1b  = (const float*)d_in[8];
  const float* bn1rm = (const float*)d_in[9];
  const float* bn1rv = (const float*)d_in[10];
  const float* W2    = (const float*)d_in[11];
  const float* as2w  = (const float*)d_in[12];
  const float* ad2w  = (const float*)d_in[13];
  const float* b2    = (const float*)d_in[14];
  const float* bn2g  = (const float*)d_in[15];
  const float* bn2b  = (const float*)d_in[16];
  const float* bn2rm = (const float*)d_in[17];
  const float* bn2rv = (const float*)d_in[18];
  const float* gateW = (const float*)d_in[19];
  const float* gateB = (const float*)d_in[20];
  const float* fc1W  = (const float*)d_in[21];
  const float* fc1b  = (const float*)d_in[22];
  const float* valW  = (const float*)d_in[23];
  const float* valb  = (const float*)d_in[24];
  const float* advW  = (const float*)d_in[25];
  const float* advb  = (const float*)d_in[26];

  int N = in_sizes[0] / 32;
  int E = in_sizes[1] / 2;
  const int* esrc = eidx;
  const int* edst = eidx + E;

  // bucket shift: NBUK = ceil(N/2^bshift) <= NBUK_MAX, bucket nodes <= 1024 (LDS limit)
  int bshift = 9;
  while ((((N - 1) >> bshift) + 1) > NBUK_MAX) ++bshift;
  int nbuk = ((N - 1) >> bshift) + 1;

  float* ws = (float*)d_ws;
  size_t o = 0;
  __half* xh1h = (__half*)(ws + o); o += (size_t)N*32;   // N*64 halves
  __half* xh2h = (__half*)(ws + o); o += (size_t)N*64;   // N*128 halves
  float* as1 = ws + o; o += (size_t)N*4;
  float* ad1 = ws + o; o += (size_t)N*4;
  float* as2 = ws + o; o += (size_t)N*4;
  float* ad2 = ws + o; o += (size_t)N*4;
  float* h1  = ws + o; o += (size_t)N*64;
  float* h2  = ws + o; o += (size_t)N*128;
  float* gate = ws + o; o += (size_t)N;
  if (o & 1) ++o;                                  // 8B align for int2
  int2* pairs = (int2*)(ws + o); o += (size_t)E*2;
  int* ib     = (int*)(ws + o);
  // zeroed block: gcnt[512], bukcnt[128], bukcur[128]
  int* gcnt   = ib;
  int* bukcnt = ib + 512;
  int* bukcur = ib + 640;
  size_t zcnt = 768;
  // non-zeroed:
  int* off    = ib + zcnt;                 // N+1
  int* goff   = off + (N+1);               // NUM_G+1
  int* bukoff = goff + (NUM_G+1);          // nbuk+1
  int* csr    = bukoff + (NBUK_MAX+1);     // E

  hipMemsetAsync(gcnt, 0, zcnt*sizeof(int), stream);

  fused_hist_lin1_kernel<<<HB+BB+L1B, 256, 0, stream>>>(
      edst, E, bukcnt, bshift, nbuk, batch, gcnt,
      x, W1, as1w, ad1w, xh1h, as1, ad1, N);
  exscan2_kernel<<<2, 1024, 0, stream>>>(bukcnt, bukoff, nbuk, gcnt, goff, NUM_G);
  int nchunk = (E + CHUNK - 1) / CHUNK;
  binscat_kernel<<<nchunk, 256, 0, stream>>>(esrc, edst, E, bukoff, bukcur, pairs, bshift, nbuk);
  bucket_csr_kernel<<<nbuk, 512, 0, stream>>>(pairs, bukoff, off, csr, N, E, bshift);
  gat_agg1_kernel<<<2048, 256, 0, stream>>>(xh1h, as1, ad1, off, csr,
      b1, bn1g, bn1b, bn1rm, bn1rv, h1, N);
  lin2_kernel<<<1024, 256, 0, stream>>>(h1, W2, as2w, ad2w, xh2h, as2, ad2, N);
  gat_agg2_kernel<<<2048, 256, 0, stream>>>(xh2h, as2, ad2, off, csr,
      b2, bn2g, bn2b, bn2rm, bn2rv, gateW, gateB, h2, gate, N);
  pool_kernel<<<NUM_G, 128, 0, stream>>>(h2, gate, goff, fc1W, fc1b, valW, valb, advW, advb,
      (float*)d_out);
}

// Round 6
// 275.413 us; speedup vs baseline: 2.3573x; 1.0569x over previous
//
#include <hip/hip_runtime.h>
#include <hip/hip_fp16.h>
#include <math.h>

#define NEG_SLOPE 0.2f
#define BN_EPS_F 1e-5f
#define NUM_G 500
#define NBUK_MAX 128
#define CHUNK 4096

__device__ __forceinline__ float leaky(float x){ return x > 0.f ? x : NEG_SLOPE*x; }
__device__ __forceinline__ float bcast(float v, int k){
  return __int_as_float(__builtin_amdgcn_readlane(__float_as_int(v), k));
}

// ============ K1: fused bucket-hist + batch-hist + lin1 (role split by blockIdx) ============
#define HB 256
#define BB 64
#define L1B 512
__global__ __launch_bounds__(256) void fused_hist_lin1_kernel(
    const int* __restrict__ edst, int E, int* __restrict__ bukcnt,
    int bshift, int nbuk,
    const int* __restrict__ batch, int* __restrict__ gcnt,
    const float* __restrict__ x, const float* __restrict__ W,
    const float* __restrict__ att_s, const float* __restrict__ att_d,
    __half* __restrict__ xh, float* __restrict__ a_src, float* __restrict__ a_dst, int N)
{
  __shared__ int lhist[NUM_G];
  int t = threadIdx.x;
  int bid = blockIdx.x;
  if (bid < HB) {
    if (t < NBUK_MAX) lhist[t] = 0;
    __syncthreads();
    int i = bid*256 + t, stride = HB*256;
    for (; i < E; i += stride) atomicAdd(&lhist[edst[i] >> bshift], 1);
    __syncthreads();
    if (t < nbuk && lhist[t]) atomicAdd(&bukcnt[t], lhist[t]);
  } else if (bid < HB + BB) {
    for (int i = t; i < NUM_G; i += 256) lhist[i] = 0;
    __syncthreads();
    int i = (bid-HB)*256 + t, stride = BB*256;
    for (; i < N; i += stride) atomicAdd(&lhist[batch[i]], 1);
    __syncthreads();
    for (int i = t; i < NUM_G; i += 256) if (lhist[i]) atomicAdd(&gcnt[i], lhist[i]);
  } else {
    int lane = t & 63;
    int wid  = ((bid - HB - BB)*256 + t) >> 6;
    int nw   = (L1B*256) >> 6;
    float w[32];
    #pragma unroll
    for (int k = 0; k < 32; ++k) w[k] = W[k*64 + lane];
    float asv = att_s[lane], adv = att_d[lane];
    for (int n = wid; n < N; n += nw) {
      float xv = (lane < 32) ? x[(size_t)n*32 + lane] : 0.f;
      float acc = 0.f;
      #pragma unroll
      for (int k = 0; k < 32; ++k) acc = fmaf(bcast(xv, k), w[k], acc);
      float sv = acc*asv, dv = acc*adv;
      #pragma unroll
      for (int m = 1; m < 16; m <<= 1) { sv += __shfl_xor(sv, m); dv += __shfl_xor(dv, m); }
      xh[(size_t)n*64 + lane] = __float2half(acc);
      if ((lane & 15) == 0) { a_src[n*4 + (lane>>4)] = sv; a_dst[n*4 + (lane>>4)] = dv; }
    }
  }
}

// ============ K2: two exclusive scans in one launch ============
__global__ __launch_bounds__(1024) void exscan2_kernel(
    const int* __restrict__ in0, int* __restrict__ out0, int n0,
    const int* __restrict__ in1, int* __restrict__ out1, int n1)
{
  const int* in  = blockIdx.x ? in1  : in0;
  int*       out = blockIdx.x ? out1 : out0;
  int        n   = blockIdx.x ? n1   : n0;
  __shared__ int part[1024];
  int t = threadIdx.x;
  int per = (n + 1023) >> 10;
  int lo = t*per, hi = lo + per; if (lo > n) lo = n; if (hi > n) hi = n;
  int s = 0;
  for (int i = lo; i < hi; ++i) s += in[i];
  part[t] = s;
  __syncthreads();
  for (int ofs = 1; ofs < 1024; ofs <<= 1) {
    int v = (t >= ofs) ? part[t-ofs] : 0;
    __syncthreads();
    part[t] += v;
    __syncthreads();
  }
  int base = part[t] - s;
  for (int i = lo; i < hi; ++i) { out[i] = base; base += in[i]; }
  if (t == 1023) out[n] = part[1023];
}

// ============ K3: binned scatter ============
__global__ __launch_bounds__(256) void binscat_kernel(
    const int* __restrict__ esrc, const int* __restrict__ edst, int E,
    const int* __restrict__ bukoff, int* __restrict__ bukcur,
    int2* __restrict__ pairs, int bshift, int nbuk)
{
  __shared__ int hist[NBUK_MAX];
  __shared__ int loffs[NBUK_MAX];
  __shared__ int gbase[NBUK_MAX];
  __shared__ int2 stage[CHUNK];
  int t = threadIdx.x;
  for (int c0 = blockIdx.x*CHUNK; c0 < E; c0 += gridDim.x*CHUNK) {
    int cnt = E - c0; if (cnt > CHUNK) cnt = CHUNK;
    if (t < NBUK_MAX) hist[t] = 0;
    __syncthreads();
    for (int i = t; i < cnt; i += 256)
      atomicAdd(&hist[edst[c0+i] >> bshift], 1);
    __syncthreads();
    int cb = (t < nbuk) ? hist[t] : 0;
    for (int ofs = 1; ofs < nbuk; ofs <<= 1) {
      int v = (t < nbuk && t >= ofs) ? hist[t-ofs] : 0;
      __syncthreads();
      if (t < nbuk) hist[t] += v;
      __syncthreads();
    }
    if (t < nbuk) {
      int lo = hist[t] - cb;
      loffs[t] = lo;
      int base = atomicAdd(&bukcur[t], cb);
      gbase[t] = bukoff[t] + base - lo;
    }
    __syncthreads();
    if (t < nbuk) hist[t] = 0;
    __syncthreads();
    for (int i = t; i < cnt; i += 256) {
      int s = esrc[c0+i], d = edst[c0+i];
      int b = d >> bshift;
      int r = atomicAdd(&hist[b], 1);
      stage[loffs[b] + r] = make_int2(s, d);
    }
    __syncthreads();
    for (int j = t; j < cnt; j += 256) {
      int2 p = stage[j];
      pairs[gbase[p.y >> bshift] + j] = p;
    }
    __syncthreads();
  }
}

// ============ K4: per-bucket CSR build ============
__global__ __launch_bounds__(512) void bucket_csr_kernel(
    const int2* __restrict__ pairs, const int* __restrict__ bukoff,
    int* __restrict__ off, int* __restrict__ csr, int N, int E, int bshift)
{
  __shared__ int cnt[1024];
  __shared__ int cur[1024];
  __shared__ int part[512];
  int b = blockIdx.x, t = threadIdx.x;
  int base = b << bshift;
  int bnodes = 1 << bshift;
  int nlocal = N - base; if (nlocal > bnodes) nlocal = bnodes;
  int lo = bukoff[b], hi = bukoff[b+1];
  int gb = lo;
  for (int i = t; i < bnodes; i += 512) cnt[i] = 0;
  __syncthreads();
  for (int i = lo + t; i < hi; i += 512) atomicAdd(&cnt[pairs[i].y - base], 1);
  __syncthreads();
  int Wc = bnodes >> 9;
  int mys = 0;
  for (int j = 0; j < Wc; ++j) mys += cnt[t*Wc + j];
  part[t] = mys;
  __syncthreads();
  for (int ofs = 1; ofs < 512; ofs <<= 1) {
    int v = (t >= ofs) ? part[t-ofs] : 0;
    __syncthreads();
    part[t] += v;
    __syncthreads();
  }
  int ex = part[t] - mys;
  for (int j = 0; j < Wc; ++j) { int c = cnt[t*Wc + j]; cnt[t*Wc + j] = ex; ex += c; }
  __syncthreads();
  for (int i = t; i < nlocal; i += 512) off[base + i] = gb + cnt[i];
  if (b == 0 && t == 0) off[N] = E;
  for (int i = t; i < bnodes; i += 512) cur[i] = 0;
  __syncthreads();
  for (int i = lo + t; i < hi; i += 512) {
    int2 p = pairs[i];
    int l = p.y - base;
    int pos = gb + cnt[l] + atomicAdd(&cur[l], 1);
    csr[pos] = p.x;
  }
}

// ============ GAT agg layer 1 (F=64): 4 edges/iter, 16 lanes/edge, 4ch/lane ============
__global__ __launch_bounds__(256) void gat_agg1_kernel(
    const __half* __restrict__ xh, const float* __restrict__ a_src, const float* __restrict__ a_dst,
    const int* __restrict__ off, const int* __restrict__ csr,
    const float* __restrict__ bias, const float* __restrict__ bng, const float* __restrict__ bnb,
    const float* __restrict__ bnrm, const float* __restrict__ bnrv,
    float* __restrict__ hout, int N)
{
  int lane = threadIdx.x & 63;
  int wid  = (blockIdx.x * blockDim.x + threadIdx.x) >> 6;
  int nw   = (gridDim.x * blockDim.x) >> 6;
  int g  = lane >> 4;        // edge slot 0..3
  int li = lane & 15;        // 16 lanes per edge
  int c0 = li * 4;           // channels c0..c0+3
  int h  = li >> 2;          // head = c0>>4
  float sc[4], of[4];
  #pragma unroll
  for (int j = 0; j < 4; ++j) {
    sc[j] = rsqrtf(bnrv[c0+j]+BN_EPS_F) * bng[c0+j];
    of[j] = bias[c0+j]*sc[j] + bnb[c0+j] - bnrm[c0+j]*sc[j];
  }
  for (int n = wid; n < N; n += nw) {
    int lo = off[n], hi = off[n+1];
    float adh = a_dst[n*4+h];
    float es  = __expf(leaky(a_src[n*4+h] + adh));
    float acc0=0.f, acc1=0.f, acc2=0.f, acc3=0.f, ssum=0.f;
    for (int e = lo; e < hi; e += 4) {
      int ee = e + g; bool ok = ee < hi;
      int s = csr[ok ? ee : lo];
      float a = a_src[s*4+h];
      int2 rv = *(const int2*)(xh + (size_t)s*64 + c0);
      float w = ok ? __expf(leaky(a+adh)) : 0.f;
      ssum += w;
      float2 f0 = __half22float2(*(__half2*)&rv.x);
      float2 f1 = __half22float2(*(__half2*)&rv.y);
      acc0 = fmaf(w, f0.x, acc0); acc1 = fmaf(w, f0.y, acc1);
      acc2 = fmaf(w, f1.x, acc2); acc3 = fmaf(w, f1.y, acc3);
    }
    #pragma unroll
    for (int m = 16; m < 64; m <<= 1) {
      acc0 += __shfl_xor(acc0, m); acc1 += __shfl_xor(acc1, m);
      acc2 += __shfl_xor(acc2, m); acc3 += __shfl_xor(acc3, m);
      ssum += __shfl_xor(ssum, m);
    }
    // self loop
    int2 rv = *(const int2*)(xh + (size_t)n*64 + c0);
    float2 f0 = __half22float2(*(__half2*)&rv.x);
    float2 f1 = __half22float2(*(__half2*)&rv.y);
    acc0 = fmaf(es, f0.x, acc0); acc1 = fmaf(es, f0.y, acc1);
    acc2 = fmaf(es, f1.x, acc2); acc3 = fmaf(es, f1.y, acc3);
    ssum += es;
    float inv = 1.f / (ssum + 1e-16f);
    if (g == 0) {
      float4 r;
      r.x = fmaxf(fmaf(acc0*inv, sc[0], of[0]), 0.f);
      r.y = fmaxf(fmaf(acc1*inv, sc[1], of[1]), 0.f);
      r.z = fmaxf(fmaf(acc2*inv, sc[2], of[2]), 0.f);
      r.w = fmaxf(fmaf(acc3*inv, sc[3], of[3]), 0.f);
      *(float4*)(hout + (size_t)n*64 + c0) = r;
    }
  }
}

// ============ linear 2 ============
__global__ __launch_bounds__(256) void lin2_kernel(
    const float* __restrict__ hin, const float* __restrict__ W,
    const float* __restrict__ att_s, const float* __restrict__ att_d,
    __half* __restrict__ xh, float* __restrict__ a_src, float* __restrict__ a_dst, int N)
{
  int lane = threadIdx.x & 63;
  int wid  = (blockIdx.x * blockDim.x + threadIdx.x) >> 6;
  int nw   = (gridDim.x * blockDim.x) >> 6;
  float wa[64], wb[64];
  #pragma unroll
  for (int k = 0; k < 64; ++k) { wa[k] = W[k*128 + lane]; wb[k] = W[k*128 + 64 + lane]; }
  float asa = att_s[lane], ada = att_d[lane];
  float asb = att_s[64+lane], adb = att_d[64+lane];
  for (int n = wid; n < N; n += nw) {
    float hv = hin[(size_t)n*64 + lane];
    float a0 = 0.f, a1 = 0.f;
    #pragma unroll
    for (int k = 0; k < 64; ++k) {
      float h = bcast(hv, k);
      a0 = fmaf(h, wa[k], a0); a1 = fmaf(h, wb[k], a1);
    }
    float sva = a0*asa, dva = a0*ada, svb = a1*asb, dvb = a1*adb;
    #pragma unroll
    for (int m = 1; m < 32; m <<= 1) {
      sva += __shfl_xor(sva, m); dva += __shfl_xor(dva, m);
      svb += __shfl_xor(svb, m); dvb += __shfl_xor(dvb, m);
    }
    xh[(size_t)n*128 + lane] = __float2half(a0);
    xh[(size_t)n*128 + 64 + lane] = __float2half(a1);
    if ((lane & 31) == 0) {
      int hh = lane >> 5;
      a_src[n*4 + hh] = sva;     a_dst[n*4 + hh] = dva;
      a_src[n*4 + 2 + hh] = svb; a_dst[n*4 + 2 + hh] = dvb;
    }
  }
}

// ============ GAT agg layer 2 (F=128): 4 edges/iter, 16 lanes/edge, 8ch/lane ============
__global__ __launch_bounds__(256) void gat_agg2_kernel(
    const __half* __restrict__ xh, const float* __restrict__ a_src, const float* __restrict__ a_dst,
    const int* __restrict__ off, const int* __restrict__ csr,
    const float* __restrict__ bias, const float* __restrict__ bng, const float* __restrict__ bnb,
    const float* __restrict__ bnrm, const float* __restrict__ bnrv,
    const float* __restrict__ gateW, const float* __restrict__ gateB,
    float* __restrict__ hout, float* __restrict__ gate, int N)
{
  int lane = threadIdx.x & 63;
  int wid  = (blockIdx.x * blockDim.x + threadIdx.x) >> 6;
  int nw   = (gridDim.x * blockDim.x) >> 6;
  int g  = lane >> 4;        // edge slot 0..3
  int li = lane & 15;        // 16 lanes per edge
  int c0 = li * 8;           // channels c0..c0+7
  int h  = li >> 2;          // head = c0>>5
  float sc[8], of[8], gw[8];
  #pragma unroll
  for (int j = 0; j < 8; ++j) {
    sc[j] = rsqrtf(bnrv[c0+j]+BN_EPS_F) * bng[c0+j];
    of[j] = bias[c0+j]*sc[j] + bnb[c0+j] - bnrm[c0+j]*sc[j];
    gw[j] = gateW[c0+j];
  }
  float gb = gateB[0];
  for (int n = wid; n < N; n += nw) {
    int lo = off[n], hi = off[n+1];
    float adh = a_dst[n*4+h];
    float es  = __expf(leaky(a_src[n*4+h] + adh));
    float acc0=0.f, acc1=0.f, acc2=0.f, acc3=0.f;
    float acc4=0.f, acc5=0.f, acc6=0.f, acc7=0.f, ssum=0.f;
    for (int e = lo; e < hi; e += 4) {
      int ee = e + g; bool ok = ee < hi;
      int s = csr[ok ? ee : lo];
      float a = a_src[s*4+h];
      int4 rv = *(const int4*)(xh + (size_t)s*128 + c0);
      float w = ok ? __expf(leaky(a+adh)) : 0.f;
      ssum += w;
      float2 f0 = __half22float2(*(__half2*)&rv.x);
      float2 f1 = __half22float2(*(__half2*)&rv.y);
      float2 f2 = __half22float2(*(__half2*)&rv.z);
      float2 f3 = __half22float2(*(__half2*)&rv.w);
      acc0 = fmaf(w, f0.x, acc0); acc1 = fmaf(w, f0.y, acc1);
      acc2 = fmaf(w, f1.x, acc2); acc3 = fmaf(w, f1.y, acc3);
      acc4 = fmaf(w, f2.x, acc4); acc5 = fmaf(w, f2.y, acc5);
      acc6 = fmaf(w, f3.x, acc6); acc7 = fmaf(w, f3.y, acc7);
    }
    #pragma unroll
    for (int m = 16; m < 64; m <<= 1) {
      acc0 += __shfl_xor(acc0, m); acc1 += __shfl_xor(acc1, m);
      acc2 += __shfl_xor(acc2, m); acc3 += __shfl_xor(acc3, m);
      acc4 += __shfl_xor(acc4, m); acc5 += __shfl_xor(acc5, m);
      acc6 += __shfl_xor(acc6, m); acc7 += __shfl_xor(acc7, m);
      ssum += __shfl_xor(ssum, m);
    }
    // self loop
    int4 rv = *(const int4*)(xh + (size_t)n*128 + c0);
    float2 f0 = __half22float2(*(__half2*)&rv.x);
    float2 f1 = __half22float2(*(__half2*)&rv.y);
    float2 f2 = __half22float2(*(__half2*)&rv.z);
    float2 f3 = __half22float2(*(__half2*)&rv.w);
    acc0 = fmaf(es, f0.x, acc0); acc1 = fmaf(es, f0.y, acc1);
    acc2 = fmaf(es, f1.x, acc2); acc3 = fmaf(es, f1.y, acc3);
    acc4 = fmaf(es, f2.x, acc4); acc5 = fmaf(es, f2.y, acc5);
    acc6 = fmaf(es, f3.x, acc6); acc7 = fmaf(es, f3.y, acc7);
    ssum += es;
    float inv = 1.f / (ssum + 1e-16f);
    float r0 = fmaxf(fmaf(acc0*inv, sc[0], of[0]), 0.f);
    float r1 = fmaxf(fmaf(acc1*inv, sc[1], of[1]), 0.f);
    float r2 = fmaxf(fmaf(acc2*inv, sc[2], of[2]), 0.f);
    float r3 = fmaxf(fmaf(acc3*inv, sc[3], of[3]), 0.f);
    float r4 = fmaxf(fmaf(acc4*inv, sc[4], of[4]), 0.f);
    float r5 = fmaxf(fmaf(acc5*inv, sc[5], of[5]), 0.f);
    float r6 = fmaxf(fmaf(acc6*inv, sc[6], of[6]), 0.f);
    float r7 = fmaxf(fmaf(acc7*inv, sc[7], of[7]), 0.f);
    if (g == 0) {
      float4 w0 = make_float4(r0, r1, r2, r3);
      float4 w1 = make_float4(r4, r5, r6, r7);
      *(float4*)(hout + (size_t)n*128 + c0)     = w0;
      *(float4*)(hout + (size_t)n*128 + c0 + 4) = w1;
    }
    // pool gate: per-lane dot over its 8 channels, reduce within the 16-lane group
    float gl = r0*gw[0] + r1*gw[1] + r2*gw[2] + r3*gw[3]
             + r4*gw[4] + r5*gw[5] + r6*gw[6] + r7*gw[7];
    #pragma unroll
    for (int m = 1; m < 16; m <<= 1) gl += __shfl_xor(gl, m);
    if (lane == 0) gate[n] = gl + gb;
  }
}

// ============ per-graph attention pooling + MLP heads ============
__global__ __launch_bounds__(128) void pool_kernel(
    const float* __restrict__ h2, const float* __restrict__ gate, const int* __restrict__ goff,
    const float* __restrict__ fc1W, const float* __restrict__ fc1b,
    const float* __restrict__ valW, const float* __restrict__ valb,
    const float* __restrict__ advW, const float* __restrict__ advb,
    float* __restrict__ out)
{
  int g = blockIdx.x, t = threadIdx.x;
  int lo = goff[g], hi = goff[g+1];
  __shared__ float red[2];
  __shared__ float pld[128];
  __shared__ float zs[32];
  __shared__ float sval;
  __shared__ float adv_s[16];

  float m = -3.4e38f;
  for (int n = lo+t; n < hi; n += 128) m = fmaxf(m, gate[n]);
  #pragma unroll
  for (int msk = 1; msk < 64; msk <<= 1) m = fmaxf(m, __shfl_xor(m, msk));
  if ((t & 63) == 0) red[t >> 6] = m;
  __syncthreads();
  m = fmaxf(red[0], red[1]);
  __syncthreads();
  float sl = 0.f;
  for (int n = lo+t; n < hi; n += 128) sl += __expf(gate[n]-m);
  #pragma unroll
  for (int msk = 1; msk < 64; msk <<= 1) sl += __shfl_xor(sl, msk);
  if ((t & 63) == 0) red[t >> 6] = sl;
  __syncthreads();
  float s = red[0] + red[1];
  float acc = 0.f;
  for (int n = lo; n < hi; ++n) {
    float w = __expf(gate[n]-m);
    acc += w * h2[(size_t)n*128 + t];
  }
  pld[t] = acc / (s + 1e-16f);
  __syncthreads();
  if (t < 32) {
    float z = fc1b[t];
    #pragma unroll 4
    for (int k = 0; k < 128; ++k) z += pld[k]*fc1W[k*32 + t];
    zs[t] = fmaxf(z, 0.f);
  }
  __syncthreads();
  if (t < 32) {
    float pv = zs[t]*valW[t];
    #pragma unroll
    for (int msk = 1; msk < 32; msk <<= 1) pv += __shfl_xor(pv, msk);
    if (t == 0) sval = pv + valb[0];
  }
  if (t < 16) {
    float a = advb[t];
    #pragma unroll
    for (int k = 0; k < 32; ++k) a += zs[k]*advW[k*16 + t];
    adv_s[t] = a;
  }
  __syncthreads();
  if (t < 16) {
    float amean = adv_s[t];
    #pragma unroll
    for (int msk = 1; msk < 16; msk <<= 1) amean += __shfl_xor(amean, msk);
    amean *= (1.f/16.f);
    out[g*16 + t] = sval + adv_s[t] - amean;
  }
}

extern "C" void kernel_launch(void* const* d_in, const int* in_sizes, int n_in,
                              void* d_out, int out_size, void* d_ws, size_t ws_size,
                              hipStream_t stream)
{
  const float* x     = (const float*)d_in[0];
  const int*   eidx  = (const int*)  d_in[1];
  const int*   batch = (const int*)  d_in[2];
  const float* W1    = (const float*)d_in[3];
  const float* as1w  = (const float*)d_in[4];
  const float* ad1w  = (const float*)d_in[5];
  const float* b1    = (const float*)d_in[6];
  const float* bn1g  = (const float*)d_in[7];
  const float* bn1b  = (const float*)d_in[8];
  const float* bn1rm = (const float*)d_in[9];
  const float* bn1rv = (const float*)d_in[10];
  const float* W2    = (const float*)d_in[11];
  const float* as2w  = (const float*)d_in[12];
  const float* ad2w  = (const float*)d_in[13];
  const float* b2    = (const float*)d_in[14];
  const float* bn2g  = (const float*)d_in[15];
  const float* bn2b  = (const float*)d_in[16];
  const float* bn2rm = (const float*)d_in[17];
  const float* bn2rv = (const float*)d_in[18];
  const float* gateW = (const float*)d_in[19];
  const float* gateB = (const float*)d_in[20];
  const float* fc1W  = (const float*)d_in[21];
  const float* fc1b  = (const float*)d_in[22];
  const float* valW  = (const float*)d_in[23];
  const float* valb  = (const float*)d_in[24];
  const float* advW  = (const float*)d_in[25];
  const float* advb  = (const float*)d_in[26];

  int N = in_sizes[0] / 32;
  int E = in_sizes[1] / 2;
  const int* esrc = eidx;
  const int* edst = eidx + E;

  int bshift = 9;
  while ((((N - 1) >> bshift) + 1) > NBUK_MAX) ++bshift;
  int nbuk = ((N - 1) >> bshift) + 1;

  float* ws = (float*)d_ws;
  size_t o = 0;
  __half* xh1h = (__half*)(ws + o); o += (size_t)N*32;   // N*64 halves
  __half* xh2h = (__half*)(ws + o); o += (size_t)N*64;   // N*128 halves
  float* as1 = ws + o; o += (size_t)N*4;
  float* ad1 = ws + o; o += (size_t)N*4;
  float* as2 = ws + o; o += (size_t)N*4;
  float* ad2 = ws + o; o += (size_t)N*4;
  float* h1  = ws + o; o += (size_t)N*64;
  float* h2  = ws + o; o += (size_t)N*128;
  float* gate = ws + o; o += (size_t)N;
  if (o & 1) ++o;
  int2* pairs = (int2*)(ws + o); o += (size_t)E*2;
  int* ib     = (int*)(ws + o);
  int* gcnt   = ib;
  int* bukcnt = ib + 512;
  int* bukcur = ib + 640;
  size_t zcnt = 768;
  int* off    = ib + zcnt;                 // N+1
  int* goff   = off + (N+1);               // NUM_G+1
  int* bukoff = goff + (NUM_G+1);          // nbuk+1
  int* csr    = bukoff + (NBUK_MAX+1);     // E

  hipMemsetAsync(gcnt, 0, zcnt*sizeof(int), stream);

  fused_hist_lin1_kernel<<<HB+BB+L1B, 256, 0, stream>>>(
      edst, E, bukcnt, bshift, nbuk, batch, gcnt,
      x, W1, as1w, ad1w, xh1h, as1, ad1, N);
  exscan2_kernel<<<2, 1024, 0, stream>>>(bukcnt, bukoff, nbuk, gcnt, goff, NUM_G);
  int nchunk = (E + CHUNK - 1) / CHUNK;
  binscat_kernel<<<nchunk, 256, 0, stream>>>(esrc, edst, E, bukoff, bukcur, pairs, bshift, nbuk);
  bucket_csr_kernel<<<nbuk, 512, 0, stream>>>(pairs, bukoff, off, csr, N, E, bshift);
  gat_agg1_kernel<<<2048, 256, 0, stream>>>(xh1h, as1, ad1, off, csr,
      b1, bn1g, bn1b, bn1rm, bn1rv, h1, N);
  lin2_kernel<<<1024, 256, 0, stream>>>(h1, W2, as2w, ad2w, xh2h, as2, ad2, N);
  gat_agg2_kernel<<<2048, 256, 0, stream>>>(xh2h, as2, ad2, off, csr,
      b2, bn2g, bn2b, bn2rm, bn2rv, gateW, gateB, h2, gate, N);
  pool_kernel<<<NUM_G, 128, 0, stream>>>(h2, gate, goff, fc1W, fc1b, valW, valb, advW, advb,
      (float*)d_out);
}

// Round 7
// 272.016 us; speedup vs baseline: 2.3867x; 1.0125x over previous
//
#include <hip/hip_runtime.h>
#include <hip/hip_fp16.h>
#include <math.h>

#define NEG_SLOPE 0.2f
#define BN_EPS_F 1e-5f
#define NUM_G 500
#define NBUK_MAX 128
#define CHUNK 4096

__device__ __forceinline__ float leaky(float x){ return x > 0.f ? x : NEG_SLOPE*x; }
__device__ __forceinline__ float bcast(float v, int k){
  return __int_as_float(__builtin_amdgcn_readlane(__float_as_int(v), k));
}

// ============ K1: fused bucket-hist + batch-hist + lin1 (role split by blockIdx) ============
#define HB 256
#define BB 64
#define L1B 512
__global__ __launch_bounds__(256) void fused_hist_lin1_kernel(
    const int* __restrict__ edst, int E, int* __restrict__ bukcnt,
    int bshift, int nbuk,
    const int* __restrict__ batch, int* __restrict__ gcnt,
    const float* __restrict__ x, const float* __restrict__ W,
    const float* __restrict__ att_s, const float* __restrict__ att_d,
    __half* __restrict__ xh, float* __restrict__ a_src, float* __restrict__ a_dst, int N)
{
  __shared__ int lhist[NUM_G];
  int t = threadIdx.x;
  int bid = blockIdx.x;
  if (bid < HB) {
    if (t < NBUK_MAX) lhist[t] = 0;
    __syncthreads();
    int i = bid*256 + t, stride = HB*256;
    for (; i < E; i += stride) atomicAdd(&lhist[edst[i] >> bshift], 1);
    __syncthreads();
    if (t < nbuk && lhist[t]) atomicAdd(&bukcnt[t], lhist[t]);
  } else if (bid < HB + BB) {
    for (int i = t; i < NUM_G; i += 256) lhist[i] = 0;
    __syncthreads();
    int i = (bid-HB)*256 + t, stride = BB*256;
    for (; i < N; i += stride) atomicAdd(&lhist[batch[i]], 1);
    __syncthreads();
    for (int i = t; i < NUM_G; i += 256) if (lhist[i]) atomicAdd(&gcnt[i], lhist[i]);
  } else {
    int lane = t & 63;
    int wid  = ((bid - HB - BB)*256 + t) >> 6;
    int nw   = (L1B*256) >> 6;
    float w[32];
    #pragma unroll
    for (int k = 0; k < 32; ++k) w[k] = W[k*64 + lane];
    float asv = att_s[lane], adv = att_d[lane];
    for (int n = wid; n < N; n += nw) {
      float xv = (lane < 32) ? x[(size_t)n*32 + lane] : 0.f;
      float acc = 0.f;
      #pragma unroll
      for (int k = 0; k < 32; ++k) acc = fmaf(bcast(xv, k), w[k], acc);
      float sv = acc*asv, dv = acc*adv;
      #pragma unroll
      for (int m = 1; m < 16; m <<= 1) { sv += __shfl_xor(sv, m); dv += __shfl_xor(dv, m); }
      xh[(size_t)n*64 + lane] = __float2half(acc);
      if ((lane & 15) == 0) { a_src[n*4 + (lane>>4)] = sv; a_dst[n*4 + (lane>>4)] = dv; }
    }
  }
}

// ============ K2: two exclusive scans in one launch ============
__global__ __launch_bounds__(1024) void exscan2_kernel(
    const int* __restrict__ in0, int* __restrict__ out0, int n0,
    const int* __restrict__ in1, int* __restrict__ out1, int n1)
{
  const int* in  = blockIdx.x ? in1  : in0;
  int*       out = blockIdx.x ? out1 : out0;
  int        n   = blockIdx.x ? n1   : n0;
  __shared__ int part[1024];
  int t = threadIdx.x;
  int per = (n + 1023) >> 10;
  int lo = t*per, hi = lo + per; if (lo > n) lo = n; if (hi > n) hi = n;
  int s = 0;
  for (int i = lo; i < hi; ++i) s += in[i];
  part[t] = s;
  __syncthreads();
  for (int ofs = 1; ofs < 1024; ofs <<= 1) {
    int v = (t >= ofs) ? part[t-ofs] : 0;
    __syncthreads();
    part[t] += v;
    __syncthreads();
  }
  int base = part[t] - s;
  for (int i = lo; i < hi; ++i) { out[i] = base; base += in[i]; }
  if (t == 1023) out[n] = part[1023];
}

// ============ K3: binned scatter ============
__global__ __launch_bounds__(256) void binscat_kernel(
    const int* __restrict__ esrc, const int* __restrict__ edst, int E,
    const int* __restrict__ bukoff, int* __restrict__ bukcur,
    int2* __restrict__ pairs, int bshift, int nbuk)
{
  __shared__ int hist[NBUK_MAX];
  __shared__ int loffs[NBUK_MAX];
  __shared__ int gbase[NBUK_MAX];
  __shared__ int2 stage[CHUNK];
  int t = threadIdx.x;
  for (int c0 = blockIdx.x*CHUNK; c0 < E; c0 += gridDim.x*CHUNK) {
    int cnt = E - c0; if (cnt > CHUNK) cnt = CHUNK;
    if (t < NBUK_MAX) hist[t] = 0;
    __syncthreads();
    for (int i = t; i < cnt; i += 256)
      atomicAdd(&hist[edst[c0+i] >> bshift], 1);
    __syncthreads();
    int cb = (t < nbuk) ? hist[t] : 0;
    for (int ofs = 1; ofs < nbuk; ofs <<= 1) {
      int v = (t < nbuk && t >= ofs) ? hist[t-ofs] : 0;
      __syncthreads();
      if (t < nbuk) hist[t] += v;
      __syncthreads();
    }
    if (t < nbuk) {
      int lo = hist[t] - cb;
      loffs[t] = lo;
      int base = atomicAdd(&bukcur[t], cb);
      gbase[t] = bukoff[t] + base - lo;
    }
    __syncthreads();
    if (t < nbuk) hist[t] = 0;
    __syncthreads();
    for (int i = t; i < cnt; i += 256) {
      int s = esrc[c0+i], d = edst[c0+i];
      int b = d >> bshift;
      int r = atomicAdd(&hist[b], 1);
      stage[loffs[b] + r] = make_int2(s, d);
    }
    __syncthreads();
    for (int j = t; j < cnt; j += 256) {
      int2 p = stage[j];
      pairs[gbase[p.y >> bshift] + j] = p;
    }
    __syncthreads();
  }
}

// ============ K4: per-bucket CSR build ============
__global__ __launch_bounds__(512) void bucket_csr_kernel(
    const int2* __restrict__ pairs, const int* __restrict__ bukoff,
    int* __restrict__ off, int* __restrict__ csr, int N, int E, int bshift)
{
  __shared__ int cnt[1024];
  __shared__ int cur[1024];
  __shared__ int part[512];
  int b = blockIdx.x, t = threadIdx.x;
  int base = b << bshift;
  int bnodes = 1 << bshift;
  int nlocal = N - base; if (nlocal > bnodes) nlocal = bnodes;
  int lo = bukoff[b], hi = bukoff[b+1];
  int gb = lo;
  for (int i = t; i < bnodes; i += 512) cnt[i] = 0;
  __syncthreads();
  for (int i = lo + t; i < hi; i += 512) atomicAdd(&cnt[pairs[i].y - base], 1);
  __syncthreads();
  int Wc = bnodes >> 9;
  int mys = 0;
  for (int j = 0; j < Wc; ++j) mys += cnt[t*Wc + j];
  part[t] = mys;
  __syncthreads();
  for (int ofs = 1; ofs < 512; ofs <<= 1) {
    int v = (t >= ofs) ? part[t-ofs] : 0;
    __syncthreads();
    part[t] += v;
    __syncthreads();
  }
  int ex = part[t] - mys;
  for (int j = 0; j < Wc; ++j) { int c = cnt[t*Wc + j]; cnt[t*Wc + j] = ex; ex += c; }
  __syncthreads();
  for (int i = t; i < nlocal; i += 512) off[base + i] = gb + cnt[i];
  if (b == 0 && t == 0) off[N] = E;
  for (int i = t; i < bnodes; i += 512) cur[i] = 0;
  __syncthreads();
  for (int i = lo + t; i < hi; i += 512) {
    int2 p = pairs[i];
    int l = p.y - base;
    int pos = gb + cnt[l] + atomicAdd(&cur[l], 1);
    csr[pos] = p.x;
  }
}

// ============ GAT agg layer 1 (F=64): 8 edges/iter (2x unroll), 16 lanes/edge, 4ch/lane ============
__global__ __launch_bounds__(256) void gat_agg1_kernel(
    const __half* __restrict__ xh, const float* __restrict__ a_src, const float* __restrict__ a_dst,
    const int* __restrict__ off, const int* __restrict__ csr,
    const float* __restrict__ bias, const float* __restrict__ bng, const float* __restrict__ bnb,
    const float* __restrict__ bnrm, const float* __restrict__ bnrv,
    float* __restrict__ hout, int N)
{
  int lane = threadIdx.x & 63;
  int wid  = (blockIdx.x * blockDim.x + threadIdx.x) >> 6;
  int nw   = (gridDim.x * blockDim.x) >> 6;
  int g  = lane >> 4;
  int li = lane & 15;
  int c0 = li * 4;
  int h  = li >> 2;
  float sc[4], of[4];
  #pragma unroll
  for (int j = 0; j < 4; ++j) {
    sc[j] = rsqrtf(bnrv[c0+j]+BN_EPS_F) * bng[c0+j];
    of[j] = bias[c0+j]*sc[j] + bnb[c0+j] - bnrm[c0+j]*sc[j];
  }
  for (int n = wid; n < N; n += nw) {
    int lo = off[n], hi = off[n+1];
    float adh = a_dst[n*4+h];
    float es  = __expf(leaky(a_src[n*4+h] + adh));
    float acc0=0.f, acc1=0.f, acc2=0.f, acc3=0.f, ssum=0.f;
    for (int e = lo; e < hi; e += 8) {
      int ee0 = e + g, ee1 = e + 4 + g;
      bool ok0 = ee0 < hi, ok1 = ee1 < hi;
      int s0 = csr[ok0 ? ee0 : lo];
      int s1 = csr[ok1 ? ee1 : lo];
      float a0 = a_src[s0*4+h];
      float a1 = a_src[s1*4+h];
      int2 rv0 = *(const int2*)(xh + (size_t)s0*64 + c0);
      int2 rv1 = *(const int2*)(xh + (size_t)s1*64 + c0);
      float w0 = ok0 ? __expf(leaky(a0+adh)) : 0.f;
      float w1 = ok1 ? __expf(leaky(a1+adh)) : 0.f;
      ssum += w0 + w1;
      float2 p0 = __half22float2(*(__half2*)&rv0.x);
      float2 p1 = __half22float2(*(__half2*)&rv0.y);
      float2 q0 = __half22float2(*(__half2*)&rv1.x);
      float2 q1 = __half22float2(*(__half2*)&rv1.y);
      acc0 = fmaf(w0, p0.x, acc0); acc1 = fmaf(w0, p0.y, acc1);
      acc2 = fmaf(w0, p1.x, acc2); acc3 = fmaf(w0, p1.y, acc3);
      acc0 = fmaf(w1, q0.x, acc0); acc1 = fmaf(w1, q0.y, acc1);
      acc2 = fmaf(w1, q1.x, acc2); acc3 = fmaf(w1, q1.y, acc3);
    }
    #pragma unroll
    for (int m = 16; m < 64; m <<= 1) {
      acc0 += __shfl_xor(acc0, m); acc1 += __shfl_xor(acc1, m);
      acc2 += __shfl_xor(acc2, m); acc3 += __shfl_xor(acc3, m);
      ssum += __shfl_xor(ssum, m);
    }
    int2 rv = *(const int2*)(xh + (size_t)n*64 + c0);
    float2 f0 = __half22float2(*(__half2*)&rv.x);
    float2 f1 = __half22float2(*(__half2*)&rv.y);
    acc0 = fmaf(es, f0.x, acc0); acc1 = fmaf(es, f0.y, acc1);
    acc2 = fmaf(es, f1.x, acc2); acc3 = fmaf(es, f1.y, acc3);
    ssum += es;
    float inv = 1.f / (ssum + 1e-16f);
    if (g == 0) {
      float4 r;
      r.x = fmaxf(fmaf(acc0*inv, sc[0], of[0]), 0.f);
      r.y = fmaxf(fmaf(acc1*inv, sc[1], of[1]), 0.f);
      r.z = fmaxf(fmaf(acc2*inv, sc[2], of[2]), 0.f);
      r.w = fmaxf(fmaf(acc3*inv, sc[3], of[3]), 0.f);
      *(float4*)(hout + (size_t)n*64 + c0) = r;
    }
  }
}

// ============ linear 2 ============
__global__ __launch_bounds__(256) void lin2_kernel(
    const float* __restrict__ hin, const float* __restrict__ W,
    const float* __restrict__ att_s, const float* __restrict__ att_d,
    __half* __restrict__ xh, float* __restrict__ a_src, float* __restrict__ a_dst, int N)
{
  int lane = threadIdx.x & 63;
  int wid  = (blockIdx.x * blockDim.x + threadIdx.x) >> 6;
  int nw   = (gridDim.x * blockDim.x) >> 6;
  float wa[64], wb[64];
  #pragma unroll
  for (int k = 0; k < 64; ++k) { wa[k] = W[k*128 + lane]; wb[k] = W[k*128 + 64 + lane]; }
  float asa = att_s[lane], ada = att_d[lane];
  float asb = att_s[64+lane], adb = att_d[64+lane];
  for (int n = wid; n < N; n += nw) {
    float hv = hin[(size_t)n*64 + lane];
    float a0 = 0.f, a1 = 0.f;
    #pragma unroll
    for (int k = 0; k < 64; ++k) {
      float h = bcast(hv, k);
      a0 = fmaf(h, wa[k], a0); a1 = fmaf(h, wb[k], a1);
    }
    float sva = a0*asa, dva = a0*ada, svb = a1*asb, dvb = a1*adb;
    #pragma unroll
    for (int m = 1; m < 32; m <<= 1) {
      sva += __shfl_xor(sva, m); dva += __shfl_xor(dva, m);
      svb += __shfl_xor(svb, m); dvb += __shfl_xor(dvb, m);
    }
    xh[(size_t)n*128 + lane] = __float2half(a0);
    xh[(size_t)n*128 + 64 + lane] = __float2half(a1);
    if ((lane & 31) == 0) {
      int hh = lane >> 5;
      a_src[n*4 + hh] = sva;     a_dst[n*4 + hh] = dva;
      a_src[n*4 + 2 + hh] = svb; a_dst[n*4 + 2 + hh] = dvb;
    }
  }
}

// ============ GAT agg layer 2 (F=128): 8 edges/iter (2x unroll), 16 lanes/edge, 8ch/lane ============
__global__ __launch_bounds__(256) void gat_agg2_kernel(
    const __half* __restrict__ xh, const float* __restrict__ a_src, const float* __restrict__ a_dst,
    const int* __restrict__ off, const int* __restrict__ csr,
    const float* __restrict__ bias, const float* __restrict__ bng, const float* __restrict__ bnb,
    const float* __restrict__ bnrm, const float* __restrict__ bnrv,
    const float* __restrict__ gateW, const float* __restrict__ gateB,
    float* __restrict__ hout, float* __restrict__ gate, int N)
{
  int lane = threadIdx.x & 63;
  int wid  = (blockIdx.x * blockDim.x + threadIdx.x) >> 6;
  int nw   = (gridDim.x * blockDim.x) >> 6;
  int g  = lane >> 4;
  int li = lane & 15;
  int c0 = li * 8;
  int h  = li >> 2;
  float sc[8], of[8], gw[8];
  #pragma unroll
  for (int j = 0; j < 8; ++j) {
    sc[j] = rsqrtf(bnrv[c0+j]+BN_EPS_F) * bng[c0+j];
    of[j] = bias[c0+j]*sc[j] + bnb[c0+j] - bnrm[c0+j]*sc[j];
    gw[j] = gateW[c0+j];
  }
  float gb = gateB[0];
  for (int n = wid; n < N; n += nw) {
    int lo = off[n], hi = off[n+1];
    float adh = a_dst[n*4+h];
    float es  = __expf(leaky(a_src[n*4+h] + adh));
    float acc0=0.f, acc1=0.f, acc2=0.f, acc3=0.f;
    float acc4=0.f, acc5=0.f, acc6=0.f, acc7=0.f, ssum=0.f;
    for (int e = lo; e < hi; e += 8) {
      int ee0 = e + g, ee1 = e + 4 + g;
      bool ok0 = ee0 < hi, ok1 = ee1 < hi;
      int s0 = csr[ok0 ? ee0 : lo];
      int s1 = csr[ok1 ? ee1 : lo];
      float a0 = a_src[s0*4+h];
      float a1 = a_src[s1*4+h];
      int4 rv0 = *(const int4*)(xh + (size_t)s0*128 + c0);
      int4 rv1 = *(const int4*)(xh + (size_t)s1*128 + c0);
      float w0 = ok0 ? __expf(leaky(a0+adh)) : 0.f;
      float w1 = ok1 ? __expf(leaky(a1+adh)) : 0.f;
      ssum += w0 + w1;
      float2 p0 = __half22float2(*(__half2*)&rv0.x);
      float2 p1 = __half22float2(*(__half2*)&rv0.y);
      float2 p2 = __half22float2(*(__half2*)&rv0.z);
      float2 p3 = __half22float2(*(__half2*)&rv0.w);
      acc0 = fmaf(w0, p0.x, acc0); acc1 = fmaf(w0, p0.y, acc1);
      acc2 = fmaf(w0, p1.x, acc2); acc3 = fmaf(w0, p1.y, acc3);
      acc4 = fmaf(w0, p2.x, acc4); acc5 = fmaf(w0, p2.y, acc5);
      acc6 = fmaf(w0, p3.x, acc6); acc7 = fmaf(w0, p3.y, acc7);
      float2 q0 = __half22float2(*(__half2*)&rv1.x);
      float2 q1 = __half22float2(*(__half2*)&rv1.y);
      float2 q2 = __half22float2(*(__half2*)&rv1.z);
      float2 q3 = __half22float2(*(__half2*)&rv1.w);
      acc0 = fmaf(w1, q0.x, acc0); acc1 = fmaf(w1, q0.y, acc1);
      acc2 = fmaf(w1, q1.x, acc2); acc3 = fmaf(w1, q1.y, acc3);
      acc4 = fmaf(w1, q2.x, acc4); acc5 = fmaf(w1, q2.y, acc5);
      acc6 = fmaf(w1, q3.x, acc6); acc7 = fmaf(w1, q3.y, acc7);
    }
    #pragma unroll
    for (int m = 16; m < 64; m <<= 1) {
      acc0 += __shfl_xor(acc0, m); acc1 += __shfl_xor(acc1, m);
      acc2 += __shfl_xor(acc2, m); acc3 += __shfl_xor(acc3, m);
      acc4 += __shfl_xor(acc4, m); acc5 += __shfl_xor(acc5, m);
      acc6 += __shfl_xor(acc6, m); acc7 += __shfl_xor(acc7, m);
      ssum += __shfl_xor(ssum, m);
    }
    int4 rv = *(const int4*)(xh + (size_t)n*128 + c0);
    float2 f0 = __half22float2(*(__half2*)&rv.x);
    float2 f1 = __half22float2(*(__half2*)&rv.y);
    float2 f2 = __half22float2(*(__half2*)&rv.z);
    float2 f3 = __half22float2(*(__half2*)&rv.w);
    acc0 = fmaf(es, f0.x, acc0); acc1 = fmaf(es, f0.y, acc1);
    acc2 = fmaf(es, f1.x, acc2); acc3 = fmaf(es, f1.y, acc3);
    acc4 = fmaf(es, f2.x, acc4); acc5 = fmaf(es, f2.y, acc5);
    acc6 = fmaf(es, f3.x, acc6); acc7 = fmaf(es, f3.y, acc7);
    ssum += es;
    float inv = 1.f / (ssum + 1e-16f);
    float r0 = fmaxf(fmaf(acc0*inv, sc[0], of[0]), 0.f);
    float r1 = fmaxf(fmaf(acc1*inv, sc[1], of[1]), 0.f);
    float r2 = fmaxf(fmaf(acc2*inv, sc[2], of[2]), 0.f);
    float r3 = fmaxf(fmaf(acc3*inv, sc[3], of[3]), 0.f);
    float r4 = fmaxf(fmaf(acc4*inv, sc[4], of[4]), 0.f);
    float r5 = fmaxf(fmaf(acc5*inv, sc[5], of[5]), 0.f);
    float r6 = fmaxf(fmaf(acc6*inv, sc[6], of[6]), 0.f);
    float r7 = fmaxf(fmaf(acc7*inv, sc[7], of[7]), 0.f);
    if (g == 0) {
      float4 w0 = make_float4(r0, r1, r2, r3);
      float4 w1 = make_float4(r4, r5, r6, r7);
      *(float4*)(hout + (size_t)n*128 + c0)     = w0;
      *(float4*)(hout + (size_t)n*128 + c0 + 4) = w1;
    }
    float gl = r0*gw[0] + r1*gw[1] + r2*gw[2] + r3*gw[3]
             + r4*gw[4] + r5*gw[5] + r6*gw[6] + r7*gw[7];
    #pragma unroll
    for (int m = 1; m < 16; m <<= 1) gl += __shfl_xor(gl, m);
    if (lane == 0) gate[n] = gl + gb;
  }
}

// ============ per-graph attention pooling + MLP heads ============
__global__ __launch_bounds__(128) void pool_kernel(
    const float* __restrict__ h2, const float* __restrict__ gate, const int* __restrict__ goff,
    const float* __restrict__ fc1W, const float* __restrict__ fc1b,
    const float* __restrict__ valW, const float* __restrict__ valb,
    const float* __restrict__ advW, const float* __restrict__ advb,
    float* __restrict__ out)
{
  int g = blockIdx.x, t = threadIdx.x;
  int lo = goff[g], hi = goff[g+1];
  __shared__ float red[2];
  __shared__ float pld[128];
  __shared__ float zs[32];
  __shared__ float sval;
  __shared__ float adv_s[16];

  float m = -3.4e38f;
  for (int n = lo+t; n < hi; n += 128) m = fmaxf(m, gate[n]);
  #pragma unroll
  for (int msk = 1; msk < 64; msk <<= 1) m = fmaxf(m, __shfl_xor(m, msk));
  if ((t & 63) == 0) red[t >> 6] = m;
  __syncthreads();
  m = fmaxf(red[0], red[1]);
  __syncthreads();
  float sl = 0.f;
  for (int n = lo+t; n < hi; n += 128) sl += __expf(gate[n]-m);
  #pragma unroll
  for (int msk = 1; msk < 64; msk <<= 1) sl += __shfl_xor(sl, msk);
  if ((t & 63) == 0) red[t >> 6] = sl;
  __syncthreads();
  float s = red[0] + red[1];
  float acc = 0.f;
  for (int n = lo; n < hi; ++n) {
    float w = __expf(gate[n]-m);
    acc += w * h2[(size_t)n*128 + t];
  }
  pld[t] = acc / (s + 1e-16f);
  __syncthreads();
  if (t < 32) {
    float z = fc1b[t];
    #pragma unroll 4
    for (int k = 0; k < 128; ++k) z += pld[k]*fc1W[k*32 + t];
    zs[t] = fmaxf(z, 0.f);
  }
  __syncthreads();
  if (t < 32) {
    float pv = zs[t]*valW[t];
    #pragma unroll
    for (int msk = 1; msk < 32; msk <<= 1) pv += __shfl_xor(pv, msk);
    if (t == 0) sval = pv + valb[0];
  }
  if (t < 16) {
    float a = advb[t];
    #pragma unroll
    for (int k = 0; k < 32; ++k) a += zs[k]*advW[k*16 + t];
    adv_s[t] = a;
  }
  __syncthreads();
  if (t < 16) {
    float amean = adv_s[t];
    #pragma unroll
    for (int msk = 1; msk < 16; msk <<= 1) amean += __shfl_xor(amean, msk);
    amean *= (1.f/16.f);
    out[g*16 + t] = sval + adv_s[t] - amean;
  }
}

extern "C" void kernel_launch(void* const* d_in, const int* in_sizes, int n_in,
                              void* d_out, int out_size, void* d_ws, size_t ws_size,
                              hipStream_t stream)
{
  const float* x     = (const float*)d_in[0];
  const int*   eidx  = (const int*)  d_in[1];
  const int*   batch = (const int*)  d_in[2];
  const float* W1    = (const float*)d_in[3];
  const float* as1w  = (const float*)d_in[4];
  const float* ad1w  = (const float*)d_in[5];
  const float* b1    = (const float*)d_in[6];
  const float* bn1g  = (const float*)d_in[7];
  const float* bn1b  = (const float*)d_in[8];
  const float* bn1rm = (const float*)d_in[9];
  const float* bn1rv = (const float*)d_in[10];
  const float* W2    = (const float*)d_in[11];
  const float* as2w  = (const float*)d_in[12];
  const float* ad2w  = (const float*)d_in[13];
  const float* b2    = (const float*)d_in[14];
  const float* bn2g  = (const float*)d_in[15];
  const float* bn2b  = (const float*)d_in[16];
  const float* bn2rm = (const float*)d_in[17];
  const float* bn2rv = (const float*)d_in[18];
  const float* gateW = (const float*)d_in[19];
  const float* gateB = (const float*)d_in[20];
  const float* fc1W  = (const float*)d_in[21];
  const float* fc1b  = (const float*)d_in[22];
  const float* valW  = (const float*)d_in[23];
  const float* valb  = (const float*)d_in[24];
  const float* advW  = (const float*)d_in[25];
  const float* advb  = (const float*)d_in[26];

  int N = in_sizes[0] / 32;
  int E = in_sizes[1] / 2;
  const int* esrc = eidx;
  const int* edst = eidx + E;

  int bshift = 9;
  while ((((N - 1) >> bshift) + 1) > NBUK_MAX) ++bshift;
  int nbuk = ((N - 1) >> bshift) + 1;

  float* ws = (float*)d_ws;
  size_t o = 0;
  __half* xh1h = (__half*)(ws + o); o += (size_t)N*32;   // N*64 halves
  __half* xh2h = (__half*)(ws + o); o += (size_t)N*64;   // N*128 halves
  float* as1 = ws + o; o += (size_t)N*4;
  float* ad1 = ws + o; o += (size_t)N*4;
  float* as2 = ws + o; o += (size_t)N*4;
  float* ad2 = ws + o; o += (size_t)N*4;
  float* h1  = ws + o; o += (size_t)N*64;
  float* h2  = ws + o; o += (size_t)N*128;
  float* gate = ws + o; o += (size_t)N;
  if (o & 1) ++o;
  int2* pairs = (int2*)(ws + o); o += (size_t)E*2;
  int* ib     = (int*)(ws + o);
  int* gcnt   = ib;
  int* bukcnt = ib + 512;
  int* bukcur = ib + 640;
  size_t zcnt = 768;
  int* off    = ib + zcnt;                 // N+1
  int* goff   = off + (N+1);               // NUM_G+1
  int* bukoff = goff + (NUM_G+1);          // nbuk+1
  int* csr    = bukoff + (NBUK_MAX+1);     // E

  hipMemsetAsync(gcnt, 0, zcnt*sizeof(int), stream);

  fused_hist_lin1_kernel<<<HB+BB+L1B, 256, 0, stream>>>(
      edst, E, bukcnt, bshift, nbuk, batch, gcnt,
      x, W1, as1w, ad1w, xh1h, as1, ad1, N);
  exscan2_kernel<<<2, 1024, 0, stream>>>(bukcnt, bukoff, nbuk, gcnt, goff, NUM_G);
  int nchunk = (E + CHUNK - 1) / CHUNK;
  binscat_kernel<<<nchunk, 256, 0, stream>>>(esrc, edst, E, bukoff, bukcur, pairs, bshift, nbuk);
  bucket_csr_kernel<<<nbuk, 512, 0, stream>>>(pairs, bukoff, off, csr, N, E, bshift);
  gat_agg1_kernel<<<2048, 256, 0, stream>>>(xh1h, as1, ad1, off, csr,
      b1, bn1g, bn1b, bn1rm, bn1rv, h1, N);
  lin2_kernel<<<1024, 256, 0, stream>>>(h1, W2, as2w, ad2w, xh2h, as2, ad2, N);
  gat_agg2_kernel<<<2048, 256, 0, stream>>>(xh2h, as2, ad2, off, csr,
      b2, bn2g, bn2b, bn2rm, bn2rv, gateW, gateB, h2, gate, N);
  pool_kernel<<<NUM_G, 128, 0, stream>>>(h2, gate, goff, fc1W, fc1b, valW, valb, advW, advb,
      (float*)d_out);
}